// Round 1
// baseline (807.172 us; speedup 1.0000x reference)
//
#include <hip/hip_runtime.h>
#include <hip/hip_bf16.h>
#include <math.h>

// DecoderBlock: graph attention message passing.
// N=20000, HID=128, H=8, C=16, E=640000.
// Phases:
//  1. CSR build by dst (hist -> scan -> scatter)
//  2. transpose weights ([Wq|Wk|Wv] -> 512x128, Wvec -> 384x128)
//  3. gemm_qkv: per-node q,k,v0,s1 (k/v depend only on src node!)
//  4. gemm_vec: per-node vec_dot, vec3, f = vec*s1
//  5. agg: one wave per dst node: online-softmax attention + vec_agg + full epilogue

#define HID 128
#define NH 8
#define NC 16

__global__ __launch_bounds__(256) void hist_kernel(const int* __restrict__ ei,
                                                   int* __restrict__ deg, int E) {
    int i = blockIdx.x * 256 + threadIdx.x;
    if (i < E) atomicAdd(&deg[ei[E + i]], 1);
}

__global__ __launch_bounds__(1024) void scan_kernel(const int* __restrict__ deg,
                                                    int* __restrict__ rowptr,
                                                    int* __restrict__ cursor, int n) {
    __shared__ int sh[1024];
    __shared__ int carryS;
    int tid = threadIdx.x;
    if (tid == 0) { carryS = 0; rowptr[0] = 0; }
    __syncthreads();
    for (int base = 0; base < n; base += 1024) {
        int i = base + tid;
        int v = (i < n) ? deg[i] : 0;
        sh[tid] = v;
        __syncthreads();
        for (int off = 1; off < 1024; off <<= 1) {
            int t = (tid >= off) ? sh[tid - off] : 0;
            __syncthreads();
            sh[tid] += t;
            __syncthreads();
        }
        int incl = sh[tid] + carryS;
        if (i < n) { rowptr[i + 1] = incl; cursor[i] = incl - v; }
        __syncthreads();
        if (tid == 1023) carryS = incl;
        __syncthreads();
    }
}

__global__ __launch_bounds__(256) void scatter_kernel(const int* __restrict__ ei,
                                                      int* __restrict__ cursor,
                                                      int* __restrict__ colb, int E) {
    int i = blockIdx.x * 256 + threadIdx.x;
    if (i < E) {
        int d = ei[E + i];
        int pos = atomicAdd(&cursor[d], 1);
        colb[pos] = ei[i];
    }
}

// WT layout: rows 0..127 = Wq cols, 128..255 = Wk cols, 256..511 = Wv cols,
//            512..895 = Wvec cols.  WT[r*128 + kk] = W[kk][col].
__global__ __launch_bounds__(256) void transpose_w(const float* __restrict__ Wq,
                                                   const float* __restrict__ Wk,
                                                   const float* __restrict__ Wv,
                                                   const float* __restrict__ Wvec,
                                                   float* __restrict__ WT) {
    int idx = blockIdx.x * 256 + threadIdx.x;
    if (idx >= 896 * 128) return;
    int r = idx >> 7, kk = idx & 127;
    float v;
    if (r < 128) v = Wq[kk * 128 + r];
    else if (r < 256) v = Wk[kk * 128 + (r - 128)];
    else if (r < 512) v = Wv[kk * 256 + (r - 256)];
    else v = Wvec[kk * 384 + (r - 512)];
    WT[idx] = v;
}

// 8 nodes/block, 256 threads. thread = (ng in {0,1} -> 4 nodes) x (cg -> 4 cols of 512).
__global__ __launch_bounds__(256) void gemm_qkv(const float* __restrict__ hin,
                                                const float* __restrict__ WT,
                                                const float* __restrict__ bq,
                                                const float* __restrict__ bk,
                                                const float* __restrict__ bv,
                                                float* __restrict__ q, float* __restrict__ k,
                                                float* __restrict__ v0, float* __restrict__ s1,
                                                int n) {
    __shared__ float sh[8 * 128];
    int n0 = blockIdx.x * 8;
    for (int i = threadIdx.x; i < 8 * 128; i += 256) {
        int nn = n0 + (i >> 7);
        sh[i] = (nn < n) ? hin[(size_t)nn * 128 + (i & 127)] : 0.f;
    }
    __syncthreads();
    int cg = threadIdx.x & 127;
    int ng = threadIdx.x >> 7;
    float acc[4][4] = {};
    const float* wbase = WT + (size_t)cg * 4 * 128;
    for (int kk = 0; kk < 128; kk += 4) {
        float4 a[4], w[4];
#pragma unroll
        for (int i = 0; i < 4; i++) a[i] = *(const float4*)&sh[(ng * 4 + i) * 128 + kk];
#pragma unroll
        for (int j = 0; j < 4; j++) w[j] = *(const float4*)&wbase[j * 128 + kk];
#pragma unroll
        for (int i = 0; i < 4; i++)
#pragma unroll
            for (int j = 0; j < 4; j++)
                acc[i][j] += a[i].x * w[j].x + a[i].y * w[j].y + a[i].z * w[j].z + a[i].w * w[j].w;
    }
#pragma unroll
    for (int j = 0; j < 4; j++) {
        int colg = cg * 4 + j;
        float bias;
        if (colg < 128) bias = bq[colg];
        else if (colg < 256) bias = bk[colg - 128];
        else bias = bv[colg - 256];
#pragma unroll
        for (int i = 0; i < 4; i++) {
            int nn = n0 + ng * 4 + i;
            if (nn >= n) continue;
            float val = acc[i][j] + bias;
            if (colg < 128) q[(size_t)nn * 128 + colg] = val;
            else if (colg < 256) k[(size_t)nn * 128 + (colg - 128)] = val;
            else {
                int vc = colg - 256;
                int hh = vc >> 5, t1 = (vc >> 4) & 1, c = vc & 15;
                float* dstp = t1 ? s1 : v0;
                dstp[(size_t)nn * 128 + hh * 16 + c] = val;
            }
        }
    }
}

// 8 nodes/block, 512 threads. thread = (g in {0..3} -> 2 nodes) x (hc of 128).
// Computes vp = vec@Wvec (j=0,1,2 slices), fuses vec_dot & vec3 & f = vec*s1.
__global__ __launch_bounds__(512) void gemm_vec(const float* __restrict__ vec,
                                                const float* __restrict__ WTv,  // 384x128
                                                const float* __restrict__ s1,
                                                float* __restrict__ vdot,
                                                float* __restrict__ vec3,
                                                float* __restrict__ f, int n) {
    __shared__ float sh[8 * 384];
    int n0 = blockIdx.x * 8;
    for (int i = threadIdx.x; i < 8 * 384; i += 512) {
        int nn = n0 + i / 384;
        sh[i] = (nn < n) ? vec[(size_t)nn * 384 + (i % 384)] : 0.f;
    }
    __syncthreads();
    int hc = threadIdx.x & 127;
    int g = threadIdx.x >> 7;
    int hh = hc >> 4, c = hc & 15;
    const float* w1 = WTv + (size_t)(hh * 48 + c) * 128;
    const float* w2 = WTv + (size_t)(hh * 48 + 16 + c) * 128;
    const float* w3 = WTv + (size_t)(hh * 48 + 32 + c) * 128;
    float y[2][3][3] = {};
    for (int kk = 0; kk < 128; kk += 4) {
        float4 wv1 = *(const float4*)&w1[kk];
        float4 wv2 = *(const float4*)&w2[kk];
        float4 wv3 = *(const float4*)&w3[kk];
#pragma unroll
        for (int nn = 0; nn < 2; nn++)
#pragma unroll
            for (int s = 0; s < 3; s++) {
                float4 a = *(const float4*)&sh[((g * 2 + nn) * 3 + s) * 128 + kk];
                y[nn][s][0] += a.x * wv1.x + a.y * wv1.y + a.z * wv1.z + a.w * wv1.w;
                y[nn][s][1] += a.x * wv2.x + a.y * wv2.y + a.z * wv2.z + a.w * wv2.w;
                y[nn][s][2] += a.x * wv3.x + a.y * wv3.y + a.z * wv3.z + a.w * wv3.w;
            }
    }
#pragma unroll
    for (int nn = 0; nn < 2; nn++) {
        int node = n0 + g * 2 + nn;
        if (node >= n) continue;
        float vd = 0.f;
#pragma unroll
        for (int s = 0; s < 3; s++) {
            vd += y[nn][s][0] * y[nn][s][1];
            vec3[(size_t)node * 384 + s * 128 + hc] = y[nn][s][2];
        }
        vdot[(size_t)node * 128 + hc] = vd;
        float sv = s1[(size_t)node * 128 + hc];
#pragma unroll
        for (int s = 0; s < 3; s++)
            f[(size_t)node * 384 + s * 128 + hc] = sh[((g * 2 + nn) * 3 + s) * 128 + hc] * sv;
    }
}

// One wave (64 lanes) per dst node; 4 waves per 256-thread block.
// lane -> channels {lane*2, lane*2+1}, both in head h = lane/8.
__global__ __launch_bounds__(256) void agg_kernel(
    const int* __restrict__ rowptr, const int* __restrict__ colb,
    const float* __restrict__ q, const float* __restrict__ k,
    const float* __restrict__ v0, const float* __restrict__ f,
    const float* __restrict__ vdot, const float* __restrict__ vec3,
    const float* __restrict__ hin, const float* __restrict__ vecin,
    const float* __restrict__ Wp, const float* __restrict__ bp,
    float* __restrict__ out0, float* __restrict__ out1, int n) {
    __shared__ float sWp[768];
    __shared__ float sbp[48];
    for (int i = threadIdx.x; i < 768; i += 256) sWp[i] = Wp[i];
    for (int i = threadIdx.x; i < 48; i += 256) sbp[i] = bp[i];
    __syncthreads();
    int lane = threadIdx.x & 63;
    int node = blockIdx.x * 4 + (threadIdx.x >> 6);
    if (node >= n) return;
    int beg = rowptr[node], end = rowptr[node + 1];
    int hc0 = lane * 2;
    float2 qv = *(const float2*)&q[(size_t)node * 128 + hc0];
    float m = -INFINITY, d = 0.f, ha0 = 0.f, ha1 = 0.f;
    float va[6] = {0.f, 0.f, 0.f, 0.f, 0.f, 0.f};
    const float L2E = 1.44269504088896f;
    for (int base = beg; base < end; base += 64) {
        int cnt = end - base;
        if (cnt > 64) cnt = 64;
        int myc = (lane < cnt) ? colb[base + lane] : 0;
        for (int e = 0; e < cnt; ++e) {
            int s = __shfl(myc, e, 64);
            float2 kv = *(const float2*)&k[(size_t)s * 128 + hc0];
            float p = qv.x * kv.x + qv.y * kv.y;
            p += __shfl_xor(p, 1, 64);
            p += __shfl_xor(p, 2, 64);
            p += __shfl_xor(p, 4, 64);
            float a = p * 0.25f;  // 1/sqrt(C)
            float nm = fmaxf(m, a);
            float scale = exp2f((m - nm) * L2E);
            float ew = exp2f((a - nm) * L2E);
            d = d * scale + ew;
            float2 vv = *(const float2*)&v0[(size_t)s * 128 + hc0];
            ha0 = ha0 * scale + ew * vv.x;
            ha1 = ha1 * scale + ew * vv.y;
            m = nm;
            const float* fp = &f[(size_t)s * 384 + hc0];
            float2 f0 = *(const float2*)&fp[0];
            float2 f1 = *(const float2*)&fp[128];
            float2 f2 = *(const float2*)&fp[256];
            va[0] += f0.x; va[1] += f0.y;
            va[2] += f1.x; va[3] += f1.y;
            va[4] += f2.x; va[5] += f2.y;
        }
    }
    float inv = (d > 0.f) ? 1.f / d : 0.f;
    float ox0 = ha0 * inv, ox1 = ha1 * inv;
    // qp = out_x[h,:] @ Wp + bp ; lane needs all 16 channels of its head.
    int c0 = (lane & 7) * 2;
    float accq[6];
#pragma unroll
    for (int jj = 0; jj < 6; jj++) {
        int j = jj >> 1, c = c0 + (jj & 1);
        accq[jj] = sbp[j * 16 + c];
    }
#pragma unroll
    for (int cp = 0; cp < 16; cp++) {
        int srcLane = (lane & 56) | (cp >> 1);
        float val = __shfl((cp & 1) ? ox1 : ox0, srcLane, 64);
#pragma unroll
        for (int jj = 0; jj < 6; jj++) {
            int j = jj >> 1, c = c0 + (jj & 1);
            accq[jj] += val * sWp[cp * 48 + j * 16 + c];
        }
    }
    // accq = [q1_0,q1_1, q2_0,q2_1, q3_0,q3_1] at this lane's channels
    float2 vd2 = *(const float2*)&vdot[(size_t)node * 128 + hc0];
    float2 hv = *(const float2*)&hin[(size_t)node * 128 + hc0];
    float2 o0;
    o0.x = hv.x + accq[2] + accq[4] * vd2.x;
    o0.y = hv.y + accq[3] + accq[5] * vd2.y;
    *(float2*)&out0[(size_t)node * 128 + hc0] = o0;
#pragma unroll
    for (int s3 = 0; s3 < 3; s3++) {
        float2 v3 = *(const float2*)&vec3[(size_t)node * 384 + s3 * 128 + hc0];
        float2 vv = *(const float2*)&vecin[(size_t)node * 384 + s3 * 128 + hc0];
        float2 o1;
        o1.x = vv.x + v3.x * accq[0] + va[s3 * 2 + 0];
        o1.y = vv.y + v3.y * accq[1] + va[s3 * 2 + 1];
        *(float2*)&out1[(size_t)node * 384 + s3 * 128 + hc0] = o1;
    }
}

extern "C" void kernel_launch(void* const* d_in, const int* in_sizes, int n_in,
                              void* d_out, int out_size, void* d_ws, size_t ws_size,
                              hipStream_t stream) {
    const float* hin = (const float*)d_in[0];
    const float* vec = (const float*)d_in[1];
    const int* ei = (const int*)d_in[2];
    const float* Wq = (const float*)d_in[3];
    const float* bq = (const float*)d_in[4];
    const float* Wk = (const float*)d_in[5];
    const float* bk = (const float*)d_in[6];
    const float* Wv = (const float*)d_in[7];
    const float* bv = (const float*)d_in[8];
    const float* Wp = (const float*)d_in[9];
    const float* bp = (const float*)d_in[10];
    const float* Wvec = (const float*)d_in[11];

    int N = in_sizes[0] / 128;
    int E = in_sizes[2] / 2;
    float* out0 = (float*)d_out;
    float* out1 = out0 + (size_t)N * 128;

    // workspace layout (floats then ints)
    float* wsf = (float*)d_ws;
    size_t off = 0;
    float* q = wsf + off;    off += (size_t)N * 128;
    float* k = wsf + off;    off += (size_t)N * 128;
    float* v0 = wsf + off;   off += (size_t)N * 128;
    float* s1 = wsf + off;   off += (size_t)N * 128;
    float* vdot = wsf + off; off += (size_t)N * 128;
    float* vec3 = wsf + off; off += (size_t)N * 384;
    float* f = wsf + off;    off += (size_t)N * 384;
    float* WT = wsf + off;   off += (size_t)896 * 128;
    int* ip = (int*)(wsf + off);
    int* deg = ip;            ip += N;
    int* rowptr = ip;         ip += N + 1;
    int* cursor = ip;         ip += N;
    int* colb = ip;           ip += E;

    hipMemsetAsync(deg, 0, (size_t)N * sizeof(int), stream);
    hipLaunchKernelGGL(hist_kernel, dim3((E + 255) / 256), dim3(256), 0, stream, ei, deg, E);
    hipLaunchKernelGGL(scan_kernel, dim3(1), dim3(1024), 0, stream, deg, rowptr, cursor, N);
    hipLaunchKernelGGL(scatter_kernel, dim3((E + 255) / 256), dim3(256), 0, stream, ei, cursor, colb, E);
    hipLaunchKernelGGL(transpose_w, dim3(448), dim3(256), 0, stream, Wq, Wk, Wv, Wvec, WT);
    hipLaunchKernelGGL(gemm_qkv, dim3((N + 7) / 8), dim3(256), 0, stream,
                       hin, WT, bq, bk, bv, q, k, v0, s1, N);
    hipLaunchKernelGGL(gemm_vec, dim3((N + 7) / 8), dim3(512), 0, stream,
                       vec, WT + 512 * 128, s1, vdot, vec3, f, N);
    hipLaunchKernelGGL(agg_kernel, dim3((N + 3) / 4), dim3(256), 0, stream,
                       rowptr, colb, q, k, v0, f, vdot, vec3, hin, vec, Wp, bp, out0, out1, N);
}

// Round 2
// 547.754 us; speedup vs baseline: 1.4736x; 1.4736x over previous
//
#include <hip/hip_runtime.h>
#include <hip/hip_bf16.h>
#include <math.h>

// DecoderBlock: graph attention message passing.
// N=20000, HID=128, H=8, C=16, E=640000.
// r2: tiled f32 GEMMs (128x128 tile, K-staged 32, 8x8 reg blocking) replace the
// weight-stationary per-node GEMMs. Cqkv[N][512] and Cvp[3N][384] are consumed
// directly by agg via column offsets. Small f-pass computes f = vec * s1.

#define HID 128
#define NH 8
#define NC 16

__global__ __launch_bounds__(256) void hist_kernel(const int* __restrict__ ei,
                                                   int* __restrict__ deg, int E) {
    int i = blockIdx.x * 256 + threadIdx.x;
    if (i < E) atomicAdd(&deg[ei[E + i]], 1);
}

__global__ __launch_bounds__(1024) void scan_kernel(const int* __restrict__ deg,
                                                    int* __restrict__ rowptr,
                                                    int* __restrict__ cursor, int n) {
    __shared__ int sh[1024];
    __shared__ int carryS;
    int tid = threadIdx.x;
    if (tid == 0) { carryS = 0; rowptr[0] = 0; }
    __syncthreads();
    for (int base = 0; base < n; base += 1024) {
        int i = base + tid;
        int v = (i < n) ? deg[i] : 0;
        sh[tid] = v;
        __syncthreads();
        for (int off = 1; off < 1024; off <<= 1) {
            int t = (tid >= off) ? sh[tid - off] : 0;
            __syncthreads();
            sh[tid] += t;
            __syncthreads();
        }
        int incl = sh[tid] + carryS;
        if (i < n) { rowptr[i + 1] = incl; cursor[i] = incl - v; }
        __syncthreads();
        if (tid == 1023) carryS = incl;
        __syncthreads();
    }
}

__global__ __launch_bounds__(256) void scatter_kernel(const int* __restrict__ ei,
                                                      int* __restrict__ cursor,
                                                      int* __restrict__ colb, int E) {
    int i = blockIdx.x * 256 + threadIdx.x;
    if (i < E) {
        int d = ei[E + i];
        int pos = atomicAdd(&cursor[d], 1);
        colb[pos] = ei[i];
    }
}

// Build WB[128][512] = [Wq|Wk|Wv] and biasAll[512] = [bq|bk|bv].
__global__ __launch_bounds__(256) void prep_kernel(const float* __restrict__ Wq,
                                                   const float* __restrict__ Wk,
                                                   const float* __restrict__ Wv,
                                                   const float* __restrict__ bq,
                                                   const float* __restrict__ bk,
                                                   const float* __restrict__ bv,
                                                   float* __restrict__ WB,
                                                   float* __restrict__ biasAll) {
    int idx = blockIdx.x * 256 + threadIdx.x;
    if (idx < 128 * 512) {
        int k = idx >> 9, c = idx & 511;
        float v;
        if (c < 128) v = Wq[k * 128 + c];
        else if (c < 256) v = Wk[k * 128 + (c - 128)];
        else v = Wv[k * 256 + (c - 256)];
        WB[idx] = v;
    } else if (idx < 128 * 512 + 512) {
        int c = idx - 128 * 512;
        float v;
        if (c < 128) v = bq[c];
        else if (c < 256) v = bk[c - 128];
        else v = bv[c - 256];
        biasAll[c] = v;
    }
}

// C[M][ldb] = A[M][128] @ B[128][ldb] (+ bias). 128x128 tile per block,
// K staged by 32, 256 threads, each computes 8 rows x 8 cols.
__global__ __launch_bounds__(256) void gemm_tiled(const float* __restrict__ A,
                                                  const float* __restrict__ B,
                                                  const float* __restrict__ bias,
                                                  float* __restrict__ C,
                                                  int M, int ldb) {
    __shared__ float sAT[32 * 132];  // [k][row], row-padded to 132
    __shared__ float sB[32 * 128];   // [k][col]
    int tid = threadIdx.x;
    int tx = tid & 15, ty = tid >> 4;
    int row0 = blockIdx.x * 128;
    int col0 = blockIdx.y * 128;

    float acc[8][8] = {};

    for (int ks = 0; ks < 4; ++ks) {
        // stage A (128 rows x 32 k), transposed into sAT[k][row]
#pragma unroll
        for (int it = 0; it < 4; ++it) {
            int idx = tid + it * 256;
            int r = idx >> 3, k4 = idx & 7;
            int grow = row0 + r;
            float4 av = make_float4(0.f, 0.f, 0.f, 0.f);
            if (grow < M) av = *(const float4*)&A[(size_t)grow * 128 + ks * 32 + k4 * 4];
            sAT[(k4 * 4 + 0) * 132 + r] = av.x;
            sAT[(k4 * 4 + 1) * 132 + r] = av.y;
            sAT[(k4 * 4 + 2) * 132 + r] = av.z;
            sAT[(k4 * 4 + 3) * 132 + r] = av.w;
        }
        // stage B (32 k x 128 cols)
#pragma unroll
        for (int it = 0; it < 4; ++it) {
            int idx = tid + it * 256;
            int k = idx >> 5, c4 = idx & 31;
            float4 bv = *(const float4*)&B[(size_t)(ks * 32 + k) * ldb + col0 + c4 * 4];
            *(float4*)&sB[k * 128 + c4 * 4] = bv;
        }
        __syncthreads();
#pragma unroll 8
        for (int k = 0; k < 32; ++k) {
            float4 a0 = *(const float4*)&sAT[k * 132 + ty * 8];
            float4 a1 = *(const float4*)&sAT[k * 132 + ty * 8 + 4];
            float4 b0 = *(const float4*)&sB[k * 128 + tx * 8];
            float4 b1 = *(const float4*)&sB[k * 128 + tx * 8 + 4];
            float aa[8] = {a0.x, a0.y, a0.z, a0.w, a1.x, a1.y, a1.z, a1.w};
            float bb[8] = {b0.x, b0.y, b0.z, b0.w, b1.x, b1.y, b1.z, b1.w};
#pragma unroll
            for (int i = 0; i < 8; ++i)
#pragma unroll
                for (int j = 0; j < 8; ++j)
                    acc[i][j] += aa[i] * bb[j];
        }
        __syncthreads();
    }

    float bv0[8];
#pragma unroll
    for (int j = 0; j < 8; ++j) bv0[j] = bias ? bias[col0 + tx * 8 + j] : 0.f;
#pragma unroll
    for (int i = 0; i < 8; ++i) {
        int row = row0 + ty * 8 + i;
        if (row >= M) continue;
        float4 c0 = make_float4(acc[i][0] + bv0[0], acc[i][1] + bv0[1],
                                acc[i][2] + bv0[2], acc[i][3] + bv0[3]);
        float4 c1 = make_float4(acc[i][4] + bv0[4], acc[i][5] + bv0[5],
                                acc[i][6] + bv0[6], acc[i][7] + bv0[7]);
        *(float4*)&C[(size_t)row * ldb + col0 + tx * 8] = c0;
        *(float4*)&C[(size_t)row * ldb + col0 + tx * 8 + 4] = c1;
    }
}

// f[n][s][hc] = vec[n][s][hc] * s1[n][hc],  s1 = Cqkv[n][256 + hh*32 + 16 + c]
__global__ __launch_bounds__(256) void f_kernel(const float* __restrict__ vec,
                                                const float* __restrict__ Cqkv,
                                                float* __restrict__ f, int n) {
    int idx4 = blockIdx.x * 256 + threadIdx.x;
    if (idx4 >= n * 96) return;
    int nn = idx4 / 96;
    int rem = idx4 - nn * 96;
    int s = rem >> 5;
    int hc0 = (rem & 31) * 4;
    int hh = hc0 >> 4, c0 = hc0 & 15;
    float4 sv = *(const float4*)&Cqkv[(size_t)nn * 512 + 256 + hh * 32 + 16 + c0];
    float4 vv = *(const float4*)&vec[((size_t)nn * 3 + s) * 128 + hc0];
    float4 ov = make_float4(vv.x * sv.x, vv.y * sv.y, vv.z * sv.z, vv.w * sv.w);
    *(float4*)&f[(size_t)nn * 384 + s * 128 + hc0] = ov;
}

// One wave (64 lanes) per dst node; 4 waves per 256-thread block.
// lane -> channels {lane*2, lane*2+1}, both in head h = lane/8.
__global__ __launch_bounds__(256) void agg_kernel(
    const int* __restrict__ rowptr, const int* __restrict__ colb,
    const float* __restrict__ Cqkv, const float* __restrict__ Cvp,
    const float* __restrict__ f,
    const float* __restrict__ hin, const float* __restrict__ vecin,
    const float* __restrict__ Wp, const float* __restrict__ bp,
    float* __restrict__ out0, float* __restrict__ out1, int n) {
    __shared__ float sWp[768];
    __shared__ float sbp[48];
    for (int i = threadIdx.x; i < 768; i += 256) sWp[i] = Wp[i];
    for (int i = threadIdx.x; i < 48; i += 256) sbp[i] = bp[i];
    __syncthreads();
    int lane = threadIdx.x & 63;
    int node = blockIdx.x * 4 + (threadIdx.x >> 6);
    if (node >= n) return;
    int beg = rowptr[node], end = rowptr[node + 1];
    int hc0 = lane * 2;
    int hh = lane >> 3, c0 = hc0 & 15;
    int vcol = 256 + (hh << 5) + c0;       // v0 column in Cqkv
    float2 qv = *(const float2*)&Cqkv[(size_t)node * 512 + hc0];
    float m = -INFINITY, d = 0.f, ha0 = 0.f, ha1 = 0.f;
    float va[6] = {0.f, 0.f, 0.f, 0.f, 0.f, 0.f};
    const float L2E = 1.44269504088896f;
    for (int base = beg; base < end; base += 64) {
        int cnt = end - base;
        if (cnt > 64) cnt = 64;
        int myc = (lane < cnt) ? colb[base + lane] : 0;
        for (int e = 0; e < cnt; ++e) {
            int s = __shfl(myc, e, 64);
            float2 kv = *(const float2*)&Cqkv[(size_t)s * 512 + 128 + hc0];
            float p = qv.x * kv.x + qv.y * kv.y;
            p += __shfl_xor(p, 1, 64);
            p += __shfl_xor(p, 2, 64);
            p += __shfl_xor(p, 4, 64);
            float a = p * 0.25f;  // 1/sqrt(C)
            float nm = fmaxf(m, a);
            float scale = exp2f((m - nm) * L2E);
            float ew = exp2f((a - nm) * L2E);
            d = d * scale + ew;
            float2 vv = *(const float2*)&Cqkv[(size_t)s * 512 + vcol];
            ha0 = ha0 * scale + ew * vv.x;
            ha1 = ha1 * scale + ew * vv.y;
            m = nm;
            const float* fp = &f[(size_t)s * 384 + hc0];
            float2 f0 = *(const float2*)&fp[0];
            float2 f1 = *(const float2*)&fp[128];
            float2 f2 = *(const float2*)&fp[256];
            va[0] += f0.x; va[1] += f0.y;
            va[2] += f1.x; va[3] += f1.y;
            va[4] += f2.x; va[5] += f2.y;
        }
    }
    float inv = (d > 0.f) ? 1.f / d : 0.f;
    float ox0 = ha0 * inv, ox1 = ha1 * inv;
    // qp = out_x[h,:] @ Wp + bp ; lane needs all 16 channels of its head.
    int cc0 = (lane & 7) * 2;
    float accq[6];
#pragma unroll
    for (int jj = 0; jj < 6; jj++) {
        int j = jj >> 1, c = cc0 + (jj & 1);
        accq[jj] = sbp[j * 16 + c];
    }
#pragma unroll
    for (int cp = 0; cp < 16; cp++) {
        int srcLane = (lane & 56) | (cp >> 1);
        float val = __shfl((cp & 1) ? ox1 : ox0, srcLane, 64);
#pragma unroll
        for (int jj = 0; jj < 6; jj++) {
            int j = jj >> 1, c = cc0 + (jj & 1);
            accq[jj] += val * sWp[cp * 48 + j * 16 + c];
        }
    }
    // accq = [q1_0,q1_1, q2_0,q2_1, q3_0,q3_1] at this lane's channels
    // vdot from Cvp: sum_s vp[...][hh*48+c] * vp[...][hh*48+16+c]
    float2 vd2 = make_float2(0.f, 0.f);
#pragma unroll
    for (int s3 = 0; s3 < 3; s3++) {
        const float* vpr = &Cvp[((size_t)node * 3 + s3) * 384 + hh * 48];
        float2 p1 = *(const float2*)&vpr[c0];
        float2 p2 = *(const float2*)&vpr[16 + c0];
        vd2.x += p1.x * p2.x;
        vd2.y += p1.y * p2.y;
    }
    float2 hv = *(const float2*)&hin[(size_t)node * 128 + hc0];
    float2 o0;
    o0.x = hv.x + accq[2] + accq[4] * vd2.x;
    o0.y = hv.y + accq[3] + accq[5] * vd2.y;
    *(float2*)&out0[(size_t)node * 128 + hc0] = o0;
#pragma unroll
    for (int s3 = 0; s3 < 3; s3++) {
        float2 v3 = *(const float2*)&Cvp[((size_t)node * 3 + s3) * 384 + hh * 48 + 32 + c0];
        float2 vv = *(const float2*)&vecin[(size_t)node * 384 + s3 * 128 + hc0];
        float2 o1;
        o1.x = vv.x + v3.x * accq[0] + va[s3 * 2 + 0];
        o1.y = vv.y + v3.y * accq[1] + va[s3 * 2 + 1];
        *(float2*)&out1[(size_t)node * 384 + s3 * 128 + hc0] = o1;
    }
}

extern "C" void kernel_launch(void* const* d_in, const int* in_sizes, int n_in,
                              void* d_out, int out_size, void* d_ws, size_t ws_size,
                              hipStream_t stream) {
    const float* hin = (const float*)d_in[0];
    const float* vec = (const float*)d_in[1];
    const int* ei = (const int*)d_in[2];
    const float* Wq = (const float*)d_in[3];
    const float* bq = (const float*)d_in[4];
    const float* Wk = (const float*)d_in[5];
    const float* bk = (const float*)d_in[6];
    const float* Wv = (const float*)d_in[7];
    const float* bv = (const float*)d_in[8];
    const float* Wp = (const float*)d_in[9];
    const float* bp = (const float*)d_in[10];
    const float* Wvec = (const float*)d_in[11];

    int N = in_sizes[0] / 128;
    int E = in_sizes[2] / 2;
    float* out0 = (float*)d_out;
    float* out1 = out0 + (size_t)N * 128;

    // workspace layout
    float* wsf = (float*)d_ws;
    size_t off = 0;
    float* Cqkv = wsf + off; off += (size_t)N * 512;
    float* Cvp = wsf + off;  off += (size_t)N * 3 * 384;
    float* f = wsf + off;    off += (size_t)N * 384;
    float* WB = wsf + off;   off += (size_t)128 * 512;
    float* biasAll = wsf + off; off += 512;
    int* ip = (int*)(wsf + off);
    int* deg = ip;            ip += N;
    int* rowptr = ip;         ip += N + 1;
    int* cursor = ip;         ip += N;
    int* colb = ip;           ip += E;

    hipMemsetAsync(deg, 0, (size_t)N * sizeof(int), stream);
    hipLaunchKernelGGL(hist_kernel, dim3((E + 255) / 256), dim3(256), 0, stream, ei, deg, E);
    hipLaunchKernelGGL(scan_kernel, dim3(1), dim3(1024), 0, stream, deg, rowptr, cursor, N);
    hipLaunchKernelGGL(scatter_kernel, dim3((E + 255) / 256), dim3(256), 0, stream, ei, cursor, colb, E);
    hipLaunchKernelGGL(prep_kernel, dim3((128 * 512 + 512 + 255) / 256), dim3(256), 0, stream,
                       Wq, Wk, Wv, bq, bk, bv, WB, biasAll);
    hipLaunchKernelGGL(gemm_tiled, dim3((N + 127) / 128, 4), dim3(256), 0, stream,
                       hin, WB, biasAll, Cqkv, N, 512);
    hipLaunchKernelGGL(gemm_tiled, dim3((3 * N + 127) / 128, 3), dim3(256), 0, stream,
                       vec, Wvec, (const float*)nullptr, Cvp, 3 * N, 384);
    hipLaunchKernelGGL(f_kernel, dim3((N * 96 + 255) / 256), dim3(256), 0, stream,
                       vec, Cqkv, f, N);
    hipLaunchKernelGGL(agg_kernel, dim3((N + 3) / 4), dim3(256), 0, stream,
                       rowptr, colb, Cqkv, Cvp, f, hin, vec, Wp, bp, out0, out1, N);
}

// Round 3
// 401.056 us; speedup vs baseline: 2.0126x; 1.3658x over previous
//
#include <hip/hip_runtime.h>
#include <hip/hip_bf16.h>
#include <math.h>

// DecoderBlock: graph attention message passing.
// N=20000, HID=128, H=8, C=16, E=640000.
// r3: agg gathers bf16-packed per-lane data (kvp: 8B/lane, fp: 12B/lane),
// 4x edge unroll with merged online-softmax max; faster single-block scan.

#define HID 128
#define NH 8
#define NC 16

static __device__ inline unsigned f2bf(float x) {
    union { float f; unsigned u; } v; v.f = x;
    return (v.u + 0x7FFFu + ((v.u >> 16) & 1u)) >> 16;
}
static __device__ inline unsigned pack2(float a, float b) {
    return f2bf(a) | (f2bf(b) << 16);
}
static __device__ inline float bflo(unsigned w) {
    union { unsigned u; float f; } v; v.u = w << 16; return v.f;
}
static __device__ inline float bfhi(unsigned w) {
    union { unsigned u; float f; } v; v.u = w & 0xFFFF0000u; return v.f;
}

__global__ __launch_bounds__(256) void hist_kernel(const int* __restrict__ ei,
                                                   int* __restrict__ deg, int E) {
    int i = blockIdx.x * 256 + threadIdx.x;
    if (i < E) atomicAdd(&deg[ei[E + i]], 1);
}

// Single block, 1024 threads, each owns 32 consecutive elements (n <= 32768).
__global__ __launch_bounds__(1024) void scan_kernel(const int* __restrict__ deg,
                                                    int* __restrict__ rowptr,
                                                    int* __restrict__ cursor, int n) {
    __shared__ int sh[1024];
    int tid = threadIdx.x;
    int base = tid * 32;
    int s = 0;
#pragma unroll
    for (int j = 0; j < 32; ++j) {
        int i = base + j;
        s += (i < n) ? deg[i] : 0;
    }
    sh[tid] = s;
    __syncthreads();
    // Hillis-Steele inclusive scan over 1024 sums
    for (int off = 1; off < 1024; off <<= 1) {
        int t = (tid >= off) ? sh[tid - off] : 0;
        __syncthreads();
        sh[tid] += t;
        __syncthreads();
    }
    int run = sh[tid] - s;  // exclusive prefix for this thread's chunk
#pragma unroll
    for (int j = 0; j < 32; ++j) {
        int i = base + j;
        if (i < n) {
            int v = deg[i];
            cursor[i] = run;
            run += v;
            rowptr[i + 1] = run;
        }
    }
    if (tid == 0) rowptr[0] = 0;
}

__global__ __launch_bounds__(256) void scatter_kernel(const int* __restrict__ ei,
                                                      int* __restrict__ cursor,
                                                      int* __restrict__ colb, int E) {
    int i = blockIdx.x * 256 + threadIdx.x;
    if (i < E) {
        int d = ei[E + i];
        int pos = atomicAdd(&cursor[d], 1);
        colb[pos] = ei[i];
    }
}

// Build WB[128][512] = [Wq|Wk|Wv] and biasAll[512] = [bq|bk|bv].
__global__ __launch_bounds__(256) void prep_kernel(const float* __restrict__ Wq,
                                                   const float* __restrict__ Wk,
                                                   const float* __restrict__ Wv,
                                                   const float* __restrict__ bq,
                                                   const float* __restrict__ bk,
                                                   const float* __restrict__ bv,
                                                   float* __restrict__ WB,
                                                   float* __restrict__ biasAll) {
    int idx = blockIdx.x * 256 + threadIdx.x;
    if (idx < 128 * 512) {
        int k = idx >> 9, c = idx & 511;
        float v;
        if (c < 128) v = Wq[k * 128 + c];
        else if (c < 256) v = Wk[k * 128 + (c - 128)];
        else v = Wv[k * 256 + (c - 256)];
        WB[idx] = v;
    } else if (idx < 128 * 512 + 512) {
        int c = idx - 128 * 512;
        float v;
        if (c < 128) v = bq[c];
        else if (c < 256) v = bk[c - 128];
        else v = bv[c - 256];
        biasAll[c] = v;
    }
}

// C[M][ldb] = A[M][128] @ B[128][ldb] (+ bias). 128x128 tile per block,
// K staged by 32, 256 threads, each computes 8 rows x 8 cols.
__global__ __launch_bounds__(256) void gemm_tiled(const float* __restrict__ A,
                                                  const float* __restrict__ B,
                                                  const float* __restrict__ bias,
                                                  float* __restrict__ C,
                                                  int M, int ldb) {
    __shared__ float sAT[32 * 132];  // [k][row], row-padded to 132
    __shared__ float sB[32 * 128];   // [k][col]
    int tid = threadIdx.x;
    int tx = tid & 15, ty = tid >> 4;
    int row0 = blockIdx.x * 128;
    int col0 = blockIdx.y * 128;

    float acc[8][8] = {};

    for (int ks = 0; ks < 4; ++ks) {
#pragma unroll
        for (int it = 0; it < 4; ++it) {
            int idx = tid + it * 256;
            int r = idx >> 3, k4 = idx & 7;
            int grow = row0 + r;
            float4 av = make_float4(0.f, 0.f, 0.f, 0.f);
            if (grow < M) av = *(const float4*)&A[(size_t)grow * 128 + ks * 32 + k4 * 4];
            sAT[(k4 * 4 + 0) * 132 + r] = av.x;
            sAT[(k4 * 4 + 1) * 132 + r] = av.y;
            sAT[(k4 * 4 + 2) * 132 + r] = av.z;
            sAT[(k4 * 4 + 3) * 132 + r] = av.w;
        }
#pragma unroll
        for (int it = 0; it < 4; ++it) {
            int idx = tid + it * 256;
            int k = idx >> 5, c4 = idx & 31;
            float4 bv = *(const float4*)&B[(size_t)(ks * 32 + k) * ldb + col0 + c4 * 4];
            *(float4*)&sB[k * 128 + c4 * 4] = bv;
        }
        __syncthreads();
#pragma unroll 8
        for (int k = 0; k < 32; ++k) {
            float4 a0 = *(const float4*)&sAT[k * 132 + ty * 8];
            float4 a1 = *(const float4*)&sAT[k * 132 + ty * 8 + 4];
            float4 b0 = *(const float4*)&sB[k * 128 + tx * 8];
            float4 b1 = *(const float4*)&sB[k * 128 + tx * 8 + 4];
            float aa[8] = {a0.x, a0.y, a0.z, a0.w, a1.x, a1.y, a1.z, a1.w};
            float bb[8] = {b0.x, b0.y, b0.z, b0.w, b1.x, b1.y, b1.z, b1.w};
#pragma unroll
            for (int i = 0; i < 8; ++i)
#pragma unroll
                for (int j = 0; j < 8; ++j)
                    acc[i][j] += aa[i] * bb[j];
        }
        __syncthreads();
    }

    float bv0[8];
#pragma unroll
    for (int j = 0; j < 8; ++j) bv0[j] = bias ? bias[col0 + tx * 8 + j] : 0.f;
#pragma unroll
    for (int i = 0; i < 8; ++i) {
        int row = row0 + ty * 8 + i;
        if (row >= M) continue;
        float4 c0 = make_float4(acc[i][0] + bv0[0], acc[i][1] + bv0[1],
                                acc[i][2] + bv0[2], acc[i][3] + bv0[3]);
        float4 c1 = make_float4(acc[i][4] + bv0[4], acc[i][5] + bv0[5],
                                acc[i][6] + bv0[6], acc[i][7] + bv0[7]);
        *(float4*)&C[(size_t)row * ldb + col0 + tx * 8] = c0;
        *(float4*)&C[(size_t)row * ldb + col0 + tx * 8 + 4] = c1;
    }
}

// One wave per node. Packs bf16 gather rows:
//  kvpU[n][128] uints: lane's uint2 = {pack2(k0,k1), pack2(v00,v01)}
//  fpU [n][192] uints: lane's uint3 = {pack2(f00,f01), pack2(f10,f11), pack2(f20,f21)}
__global__ __launch_bounds__(256) void pack_kernel(const float* __restrict__ Cqkv,
                                                   const float* __restrict__ vec,
                                                   unsigned* __restrict__ kvpU,
                                                   unsigned* __restrict__ fpU, int n) {
    int lane = threadIdx.x & 63;
    int node = blockIdx.x * 4 + (threadIdx.x >> 6);
    if (node >= n) return;
    int hc0 = lane * 2, hh = lane >> 3, c0 = hc0 & 15;
    const float* row = &Cqkv[(size_t)node * 512];
    float2 kk = *(const float2*)&row[128 + hc0];
    float2 v0 = *(const float2*)&row[256 + hh * 32 + c0];
    float2 s1 = *(const float2*)&row[256 + hh * 32 + 16 + c0];
    uint2 kvw;
    kvw.x = pack2(kk.x, kk.y);
    kvw.y = pack2(v0.x, v0.y);
    *(uint2*)&kvpU[(size_t)node * 128 + lane * 2] = kvw;
    uint3 fw;
    float2 a0 = *(const float2*)&vec[(size_t)node * 384 + 0 * 128 + hc0];
    float2 a1 = *(const float2*)&vec[(size_t)node * 384 + 1 * 128 + hc0];
    float2 a2 = *(const float2*)&vec[(size_t)node * 384 + 2 * 128 + hc0];
    fw.x = pack2(a0.x * s1.x, a0.y * s1.y);
    fw.y = pack2(a1.x * s1.x, a1.y * s1.y);
    fw.z = pack2(a2.x * s1.x, a2.y * s1.y);
    *(uint3*)&fpU[(size_t)node * 192 + lane * 3] = fw;
}

// One wave (64 lanes) per dst node; 4 waves per 256-thread block.
// lane -> channels {lane*2, lane*2+1}, head h = lane/8.
__global__ __launch_bounds__(256) void agg_kernel(
    const int* __restrict__ rowptr, const int* __restrict__ colb,
    const float* __restrict__ Cqkv, const float* __restrict__ Cvp,
    const unsigned* __restrict__ kvpU, const unsigned* __restrict__ fpU,
    const float* __restrict__ hin, const float* __restrict__ vecin,
    const float* __restrict__ Wp, const float* __restrict__ bp,
    float* __restrict__ out0, float* __restrict__ out1, int n) {
    __shared__ float sWp[768];
    __shared__ float sbp[48];
    for (int i = threadIdx.x; i < 768; i += 256) sWp[i] = Wp[i];
    for (int i = threadIdx.x; i < 48; i += 256) sbp[i] = bp[i];
    __syncthreads();
    int lane = threadIdx.x & 63;
    int node = blockIdx.x * 4 + (threadIdx.x >> 6);
    if (node >= n) return;
    int beg = rowptr[node], end = rowptr[node + 1];
    int hc0 = lane * 2;
    int hh = lane >> 3, c0 = hc0 & 15;
    float2 qv = *(const float2*)&Cqkv[(size_t)node * 512 + hc0];
    float m = -INFINITY, d = 0.f, ha0 = 0.f, ha1 = 0.f;
    float va[6] = {0.f, 0.f, 0.f, 0.f, 0.f, 0.f};
    const float L2E = 1.44269504088896f;
    for (int base = beg; base < end; base += 64) {
        int cnt = end - base;
        if (cnt > 64) cnt = 64;
        int myc = (lane < cnt) ? colb[base + lane] : 0;
        int e = 0;
        for (; e + 3 < cnt; e += 4) {
            int s0 = __shfl(myc, e, 64);
            int s1i = __shfl(myc, e + 1, 64);
            int s2i = __shfl(myc, e + 2, 64);
            int s3i = __shfl(myc, e + 3, 64);
            uint2 w0 = *(const uint2*)&kvpU[(size_t)s0 * 128 + lane * 2];
            uint2 w1 = *(const uint2*)&kvpU[(size_t)s1i * 128 + lane * 2];
            uint2 w2 = *(const uint2*)&kvpU[(size_t)s2i * 128 + lane * 2];
            uint2 w3 = *(const uint2*)&kvpU[(size_t)s3i * 128 + lane * 2];
            uint3 g0 = *(const uint3*)&fpU[(size_t)s0 * 192 + lane * 3];
            uint3 g1 = *(const uint3*)&fpU[(size_t)s1i * 192 + lane * 3];
            uint3 g2 = *(const uint3*)&fpU[(size_t)s2i * 192 + lane * 3];
            uint3 g3 = *(const uint3*)&fpU[(size_t)s3i * 192 + lane * 3];
            float p0 = qv.x * bflo(w0.x) + qv.y * bfhi(w0.x);
            float p1 = qv.x * bflo(w1.x) + qv.y * bfhi(w1.x);
            float p2 = qv.x * bflo(w2.x) + qv.y * bfhi(w2.x);
            float p3 = qv.x * bflo(w3.x) + qv.y * bfhi(w3.x);
            p0 += __shfl_xor(p0, 1, 64); p0 += __shfl_xor(p0, 2, 64); p0 += __shfl_xor(p0, 4, 64);
            p1 += __shfl_xor(p1, 1, 64); p1 += __shfl_xor(p1, 2, 64); p1 += __shfl_xor(p1, 4, 64);
            p2 += __shfl_xor(p2, 1, 64); p2 += __shfl_xor(p2, 2, 64); p2 += __shfl_xor(p2, 4, 64);
            p3 += __shfl_xor(p3, 1, 64); p3 += __shfl_xor(p3, 2, 64); p3 += __shfl_xor(p3, 4, 64);
            float a0 = p0 * 0.25f, a1 = p1 * 0.25f, a2 = p2 * 0.25f, a3 = p3 * 0.25f;
            float nm = fmaxf(fmaxf(fmaxf(a0, a1), fmaxf(a2, a3)), m);
            float sc = exp2f((m - nm) * L2E);
            float e0 = exp2f((a0 - nm) * L2E);
            float e1 = exp2f((a1 - nm) * L2E);
            float e2 = exp2f((a2 - nm) * L2E);
            float e3 = exp2f((a3 - nm) * L2E);
            d = d * sc + e0 + e1 + e2 + e3;
            ha0 = ha0 * sc + e0 * bflo(w0.y) + e1 * bflo(w1.y) + e2 * bflo(w2.y) + e3 * bflo(w3.y);
            ha1 = ha1 * sc + e0 * bfhi(w0.y) + e1 * bfhi(w1.y) + e2 * bfhi(w2.y) + e3 * bfhi(w3.y);
            m = nm;
            va[0] += bflo(g0.x) + bflo(g1.x) + bflo(g2.x) + bflo(g3.x);
            va[1] += bfhi(g0.x) + bfhi(g1.x) + bfhi(g2.x) + bfhi(g3.x);
            va[2] += bflo(g0.y) + bflo(g1.y) + bflo(g2.y) + bflo(g3.y);
            va[3] += bfhi(g0.y) + bfhi(g1.y) + bfhi(g2.y) + bfhi(g3.y);
            va[4] += bflo(g0.z) + bflo(g1.z) + bflo(g2.z) + bflo(g3.z);
            va[5] += bfhi(g0.z) + bfhi(g1.z) + bfhi(g2.z) + bfhi(g3.z);
        }
        for (; e < cnt; ++e) {
            int s0 = __shfl(myc, e, 64);
            uint2 w0 = *(const uint2*)&kvpU[(size_t)s0 * 128 + lane * 2];
            uint3 g0 = *(const uint3*)&fpU[(size_t)s0 * 192 + lane * 3];
            float p0 = qv.x * bflo(w0.x) + qv.y * bfhi(w0.x);
            p0 += __shfl_xor(p0, 1, 64); p0 += __shfl_xor(p0, 2, 64); p0 += __shfl_xor(p0, 4, 64);
            float a0 = p0 * 0.25f;
            float nm = fmaxf(m, a0);
            float sc = exp2f((m - nm) * L2E);
            float e0 = exp2f((a0 - nm) * L2E);
            d = d * sc + e0;
            ha0 = ha0 * sc + e0 * bflo(w0.y);
            ha1 = ha1 * sc + e0 * bfhi(w0.y);
            m = nm;
            va[0] += bflo(g0.x); va[1] += bfhi(g0.x);
            va[2] += bflo(g0.y); va[3] += bfhi(g0.y);
            va[4] += bflo(g0.z); va[5] += bfhi(g0.z);
        }
    }
    float inv = (d > 0.f) ? 1.f / d : 0.f;
    float ox0 = ha0 * inv, ox1 = ha1 * inv;
    // qp = out_x[h,:] @ Wp + bp ; lane needs all 16 channels of its head.
    int cc0 = (lane & 7) * 2;
    float accq[6];
#pragma unroll
    for (int jj = 0; jj < 6; jj++) {
        int j = jj >> 1, c = cc0 + (jj & 1);
        accq[jj] = sbp[j * 16 + c];
    }
#pragma unroll
    for (int cp = 0; cp < 16; cp++) {
        int srcLane = (lane & 56) | (cp >> 1);
        float val = __shfl((cp & 1) ? ox1 : ox0, srcLane, 64);
#pragma unroll
        for (int jj = 0; jj < 6; jj++) {
            int j = jj >> 1, c = cc0 + (jj & 1);
            accq[jj] += val * sWp[cp * 48 + j * 16 + c];
        }
    }
    // vdot from Cvp: sum_s vp[..][hh*48+c] * vp[..][hh*48+16+c]
    float2 vd2 = make_float2(0.f, 0.f);
#pragma unroll
    for (int s3 = 0; s3 < 3; s3++) {
        const float* vpr = &Cvp[((size_t)node * 3 + s3) * 384 + hh * 48];
        float2 p1 = *(const float2*)&vpr[c0];
        float2 p2 = *(const float2*)&vpr[16 + c0];
        vd2.x += p1.x * p2.x;
        vd2.y += p1.y * p2.y;
    }
    float2 hv = *(const float2*)&hin[(size_t)node * 128 + hc0];
    float2 o0;
    o0.x = hv.x + accq[2] + accq[4] * vd2.x;
    o0.y = hv.y + accq[3] + accq[5] * vd2.y;
    *(float2*)&out0[(size_t)node * 128 + hc0] = o0;
#pragma unroll
    for (int s3 = 0; s3 < 3; s3++) {
        float2 v3 = *(const float2*)&Cvp[((size_t)node * 3 + s3) * 384 + hh * 48 + 32 + c0];
        float2 vv = *(const float2*)&vecin[(size_t)node * 384 + s3 * 128 + hc0];
        float2 o1;
        o1.x = vv.x + v3.x * accq[0] + va[s3 * 2 + 0];
        o1.y = vv.y + v3.y * accq[1] + va[s3 * 2 + 1];
        *(float2*)&out1[(size_t)node * 384 + s3 * 128 + hc0] = o1;
    }
}

extern "C" void kernel_launch(void* const* d_in, const int* in_sizes, int n_in,
                              void* d_out, int out_size, void* d_ws, size_t ws_size,
                              hipStream_t stream) {
    const float* hin = (const float*)d_in[0];
    const float* vec = (const float*)d_in[1];
    const int* ei = (const int*)d_in[2];
    const float* Wq = (const float*)d_in[3];
    const float* bq = (const float*)d_in[4];
    const float* Wk = (const float*)d_in[5];
    const float* bk = (const float*)d_in[6];
    const float* Wv = (const float*)d_in[7];
    const float* bv = (const float*)d_in[8];
    const float* Wp = (const float*)d_in[9];
    const float* bp = (const float*)d_in[10];
    const float* Wvec = (const float*)d_in[11];

    int N = in_sizes[0] / 128;
    int E = in_sizes[2] / 2;
    float* out0 = (float*)d_out;
    float* out1 = out0 + (size_t)N * 128;

    // workspace layout
    float* wsf = (float*)d_ws;
    size_t off = 0;
    float* Cqkv = wsf + off; off += (size_t)N * 512;
    float* Cvp = wsf + off;  off += (size_t)N * 3 * 384;
    unsigned* kvpU = (unsigned*)(wsf + off); off += (size_t)N * 128;
    unsigned* fpU = (unsigned*)(wsf + off);  off += (size_t)N * 192;
    float* WB = wsf + off;   off += (size_t)128 * 512;
    float* biasAll = wsf + off; off += 512;
    int* ip = (int*)(wsf + off);
    int* deg = ip;            ip += N;
    int* rowptr = ip;         ip += N + 1;
    int* cursor = ip;         ip += N;
    int* colb = ip;           ip += E;

    hipMemsetAsync(deg, 0, (size_t)N * sizeof(int), stream);
    hipLaunchKernelGGL(hist_kernel, dim3((E + 255) / 256), dim3(256), 0, stream, ei, deg, E);
    hipLaunchKernelGGL(scan_kernel, dim3(1), dim3(1024), 0, stream, deg, rowptr, cursor, N);
    hipLaunchKernelGGL(scatter_kernel, dim3((E + 255) / 256), dim3(256), 0, stream, ei, cursor, colb, E);
    hipLaunchKernelGGL(prep_kernel, dim3((128 * 512 + 512 + 255) / 256), dim3(256), 0, stream,
                       Wq, Wk, Wv, bq, bk, bv, WB, biasAll);
    hipLaunchKernelGGL(gemm_tiled, dim3((N + 127) / 128, 4), dim3(256), 0, stream,
                       hin, WB, biasAll, Cqkv, N, 512);
    hipLaunchKernelGGL(gemm_tiled, dim3((3 * N + 127) / 128, 3), dim3(256), 0, stream,
                       vec, Wvec, (const float*)nullptr, Cvp, 3 * N, 384);
    hipLaunchKernelGGL(pack_kernel, dim3((N + 3) / 4), dim3(256), 0, stream,
                       Cqkv, vec, kvpU, fpU, N);
    hipLaunchKernelGGL(agg_kernel, dim3((N + 3) / 4), dim3(256), 0, stream,
                       rowptr, colb, Cqkv, Cvp, kvpU, fpU, hin, vec, Wp, bp, out0, out1, N);
}

// Round 4
// 330.874 us; speedup vs baseline: 2.4395x; 1.2121x over previous
//
#include <hip/hip_runtime.h>
#include <hip/hip_bf16.h>
#include <math.h>

// DecoderBlock: graph attention message passing.
// N=20000, HID=128, H=8, C=16, E=640000.
// r4: MFMA bf16 GEMMs (16x16x32) for qkv and vec projections; agg gathers one
// merged 20B/lane row (kv + f) with 8x edge unroll for deep MLP.

typedef __attribute__((ext_vector_type(8))) short bf16x8;
typedef __attribute__((ext_vector_type(4))) float f32x4;

static __device__ inline unsigned f2bf(float x) {
    union { float f; unsigned u; } v; v.f = x;
    return (v.u + 0x7FFFu + ((v.u >> 16) & 1u)) >> 16;
}
static __device__ inline unsigned pack2(float a, float b) {
    return f2bf(a) | (f2bf(b) << 16);
}
static __device__ inline float bflo(unsigned w) {
    union { unsigned u; float f; } v; v.u = w << 16; return v.f;
}
static __device__ inline float bfhi(unsigned w) {
    union { unsigned u; float f; } v; v.u = w & 0xFFFF0000u; return v.f;
}

__global__ __launch_bounds__(256) void hist_kernel(const int* __restrict__ ei,
                                                   int* __restrict__ deg, int E) {
    int i = blockIdx.x * 256 + threadIdx.x;
    if (i < E) atomicAdd(&deg[ei[E + i]], 1);
}

// Single block, 1024 threads, each owns 32 consecutive elements (n <= 32768).
__global__ __launch_bounds__(1024) void scan_kernel(const int* __restrict__ deg,
                                                    int* __restrict__ rowptr,
                                                    int* __restrict__ cursor, int n) {
    __shared__ int sh[1024];
    int tid = threadIdx.x;
    int base = tid * 32;
    int s = 0;
#pragma unroll
    for (int j = 0; j < 32; ++j) {
        int i = base + j;
        s += (i < n) ? deg[i] : 0;
    }
    sh[tid] = s;
    __syncthreads();
    for (int off = 1; off < 1024; off <<= 1) {
        int t = (tid >= off) ? sh[tid - off] : 0;
        __syncthreads();
        sh[tid] += t;
        __syncthreads();
    }
    int run = sh[tid] - s;
#pragma unroll
    for (int j = 0; j < 32; ++j) {
        int i = base + j;
        if (i < n) {
            int v = deg[i];
            cursor[i] = run;
            run += v;
            rowptr[i + 1] = run;
        }
    }
    if (tid == 0) rowptr[0] = 0;
}

__global__ __launch_bounds__(256) void scatter_kernel(const int* __restrict__ ei,
                                                      int* __restrict__ cursor,
                                                      int* __restrict__ colb, int E) {
    int i = blockIdx.x * 256 + threadIdx.x;
    if (i < E) {
        int d = ei[E + i];
        int pos = atomicAdd(&cursor[d], 1);
        colb[pos] = ei[i];
    }
}

// WBT[512][128] bf16: col-major-of-[Wq|Wk|Wv]; WVT[384][128] bf16: Wvec^T;
// biasAll[512] f32.
__global__ __launch_bounds__(256) void prep_kernel(const float* __restrict__ Wq,
                                                   const float* __restrict__ Wk,
                                                   const float* __restrict__ Wv,
                                                   const float* __restrict__ Wvec,
                                                   const float* __restrict__ bq,
                                                   const float* __restrict__ bk,
                                                   const float* __restrict__ bv,
                                                   unsigned short* __restrict__ WBT,
                                                   unsigned short* __restrict__ WVT,
                                                   float* __restrict__ biasAll) {
    int idx = blockIdx.x * 256 + threadIdx.x;
    if (idx < 512 * 128) {
        int c = idx >> 7, k = idx & 127;
        float v;
        if (c < 128) v = Wq[k * 128 + c];
        else if (c < 256) v = Wk[k * 128 + (c - 128)];
        else v = Wv[k * 256 + (c - 256)];
        WBT[idx] = (unsigned short)f2bf(v);
    } else if (idx < 512 * 128 + 384 * 128) {
        int j = idx - 512 * 128;
        int c = j >> 7, k = j & 127;
        WVT[j] = (unsigned short)f2bf(Wvec[k * 384 + c]);
    } else if (idx < 512 * 128 + 384 * 128 + 512) {
        int c = idx - (512 * 128 + 384 * 128);
        biasAll[c] = (c < 128) ? bq[c] : (c < 256) ? bk[c - 128] : bv[c - 256];
    }
}

// C[M][ldc] = A[M][128](f32,cvt->bf16) @ B[128][ldc](bf16, given as BT[col][k]).
// 128x128 tile, K=128 in one shot. 4 waves, each 64x64 (4x4 frags of 16x16x32).
// LDS pitch 136 shorts (272B) -> frag ds_read_b128 <=2-way bank conflict.
__global__ __launch_bounds__(256) void gemm_mfma(const float* __restrict__ A,
                                                 const unsigned short* __restrict__ BT,
                                                 const float* __restrict__ bias,
                                                 float* __restrict__ C, int M, int ldc) {
    __shared__ unsigned short sA[128 * 136];
    __shared__ unsigned short sB[128 * 136];
    int tid = threadIdx.x;
    int row0 = blockIdx.x * 128, col0 = blockIdx.y * 128;
#pragma unroll
    for (int i = 0; i < 8; ++i) {
        int id = tid + i * 256;        // 0..2047
        int r = id >> 4, cof = id & 15;
        uint4 wa = make_uint4(0u, 0u, 0u, 0u);
        int grow = row0 + r;
        if (grow < M) {
            const float* ap = &A[(size_t)grow * 128 + cof * 8];
            float4 x0 = *(const float4*)ap;
            float4 x1 = *(const float4*)(ap + 4);
            wa.x = pack2(x0.x, x0.y); wa.y = pack2(x0.z, x0.w);
            wa.z = pack2(x1.x, x1.y); wa.w = pack2(x1.z, x1.w);
        }
        *(uint4*)&sA[r * 136 + cof * 8] = wa;
        uint4 wb = *(const uint4*)&BT[((size_t)(col0 + r)) * 128 + cof * 8];
        *(uint4*)&sB[r * 136 + cof * 8] = wb;
    }
    __syncthreads();
    int wid = tid >> 6, lane = tid & 63;
    int wr = (wid >> 1) * 64, wc = (wid & 1) * 64;
    int lr = lane & 15, lk = lane >> 4;
    f32x4 acc[4][4] = {};
#pragma unroll
    for (int ks = 0; ks < 4; ++ks) {
        bf16x8 af[4], bfr[4];
#pragma unroll
        for (int mm = 0; mm < 4; ++mm)
            af[mm] = *(const bf16x8*)&sA[(wr + mm * 16 + lr) * 136 + ks * 32 + lk * 8];
#pragma unroll
        for (int nn = 0; nn < 4; ++nn)
            bfr[nn] = *(const bf16x8*)&sB[(wc + nn * 16 + lr) * 136 + ks * 32 + lk * 8];
#pragma unroll
        for (int mm = 0; mm < 4; ++mm)
#pragma unroll
            for (int nn = 0; nn < 4; ++nn)
                acc[mm][nn] = __builtin_amdgcn_mfma_f32_16x16x32_bf16(af[mm], bfr[nn],
                                                                     acc[mm][nn], 0, 0, 0);
    }
#pragma unroll
    for (int mm = 0; mm < 4; ++mm) {
#pragma unroll
        for (int r4 = 0; r4 < 4; ++r4) {
            int row = row0 + wr + mm * 16 + lk * 4 + r4;
            if (row >= M) continue;
#pragma unroll
            for (int nn = 0; nn < 4; ++nn) {
                int col = col0 + wc + nn * 16 + lr;
                float v = acc[mm][nn][r4];
                if (bias) v += bias[col];
                C[(size_t)row * ldc + col] = v;
            }
        }
    }
}

// Merged gather row: nodeP[n] = 320 uints (1280B). Lane's 5 uints at lane*5:
// {pack2(k0,k1), pack2(v00,v01), pack2(f00,f01), pack2(f10,f11), pack2(f20,f21)}
__global__ __launch_bounds__(256) void pack_kernel(const float* __restrict__ Cqkv,
                                                   const float* __restrict__ vec,
                                                   unsigned* __restrict__ nodeP, int n) {
    int lane = threadIdx.x & 63;
    int node = blockIdx.x * 4 + (threadIdx.x >> 6);
    if (node >= n) return;
    int hc0 = lane * 2, hh = lane >> 3, c0 = hc0 & 15;
    const float* row = &Cqkv[(size_t)node * 512];
    float2 kk = *(const float2*)&row[128 + hc0];
    float2 v0 = *(const float2*)&row[256 + hh * 32 + c0];
    float2 s1 = *(const float2*)&row[256 + hh * 32 + 16 + c0];
    float2 a0 = *(const float2*)&vec[(size_t)node * 384 + 0 * 128 + hc0];
    float2 a1 = *(const float2*)&vec[(size_t)node * 384 + 1 * 128 + hc0];
    float2 a2 = *(const float2*)&vec[(size_t)node * 384 + 2 * 128 + hc0];
    unsigned* rp = &nodeP[(size_t)node * 320 + lane * 5];
    uint4 w;
    w.x = pack2(kk.x, kk.y);
    w.y = pack2(v0.x, v0.y);
    w.z = pack2(a0.x * s1.x, a0.y * s1.y);
    w.w = pack2(a1.x * s1.x, a1.y * s1.y);
    *(uint4*)rp = w;
    rp[4] = pack2(a2.x * s1.x, a2.y * s1.y);
}

// One wave per dst node; 4 waves per block. lane -> channels {2*lane, 2*lane+1}.
__global__ __launch_bounds__(256) void agg_kernel(
    const int* __restrict__ rowptr, const int* __restrict__ colb,
    const float* __restrict__ Cqkv, const float* __restrict__ Cvp,
    const unsigned* __restrict__ nodeP,
    const float* __restrict__ hin, const float* __restrict__ vecin,
    const float* __restrict__ Wp, const float* __restrict__ bp,
    float* __restrict__ out0, float* __restrict__ out1, int n) {
    __shared__ float sWp[768];
    __shared__ float sbp[48];
    for (int i = threadIdx.x; i < 768; i += 256) sWp[i] = Wp[i];
    for (int i = threadIdx.x; i < 48; i += 256) sbp[i] = bp[i];
    __syncthreads();
    int lane = threadIdx.x & 63;
    int node = blockIdx.x * 4 + (threadIdx.x >> 6);
    if (node >= n) return;
    int beg = rowptr[node], end = rowptr[node + 1];
    int hc0 = lane * 2;
    int hh = lane >> 3, c0 = hc0 & 15;
    int lane5 = lane * 5;
    float2 qv = *(const float2*)&Cqkv[(size_t)node * 512 + hc0];
    float m = -INFINITY, d = 0.f, ha0 = 0.f, ha1 = 0.f;
    float va[6] = {0.f, 0.f, 0.f, 0.f, 0.f, 0.f};
    const float L2E = 1.44269504088896f;
    for (int base = beg; base < end; base += 64) {
        int cnt = end - base;
        if (cnt > 64) cnt = 64;
        int myc = (lane < cnt) ? colb[base + lane] : 0;
        int e = 0;
        for (; e + 7 < cnt; e += 8) {
            uint4 w[8]; unsigned g2[8];
#pragma unroll
            for (int u = 0; u < 8; ++u) {
                int s = __shfl(myc, e + u, 64);
                const unsigned* rp = &nodeP[(size_t)s * 320 + lane5];
                w[u] = *(const uint4*)rp;
                g2[u] = rp[4];
            }
            float p[8];
#pragma unroll
            for (int u = 0; u < 8; ++u) {
                float t = qv.x * bflo(w[u].x) + qv.y * bfhi(w[u].x);
                t += __shfl_xor(t, 1, 64);
                t += __shfl_xor(t, 2, 64);
                t += __shfl_xor(t, 4, 64);
                p[u] = t * 0.25f;
            }
            float nm = fmaxf(fmaxf(fmaxf(p[0], p[1]), fmaxf(p[2], p[3])),
                             fmaxf(fmaxf(p[4], p[5]), fmaxf(p[6], p[7])));
            nm = fmaxf(nm, m);
            float sc = exp2f((m - nm) * L2E);
            float ex[8];
#pragma unroll
            for (int u = 0; u < 8; ++u) ex[u] = exp2f((p[u] - nm) * L2E);
            float ds = ((ex[0] + ex[1]) + (ex[2] + ex[3])) + ((ex[4] + ex[5]) + (ex[6] + ex[7]));
            d = d * sc + ds;
            float s0 = 0.f, s1a = 0.f;
#pragma unroll
            for (int u = 0; u < 8; ++u) {
                s0 += ex[u] * bflo(w[u].y);
                s1a += ex[u] * bfhi(w[u].y);
            }
            ha0 = ha0 * sc + s0;
            ha1 = ha1 * sc + s1a;
            m = nm;
#pragma unroll
            for (int u = 0; u < 8; ++u) {
                va[0] += bflo(w[u].z); va[1] += bfhi(w[u].z);
                va[2] += bflo(w[u].w); va[3] += bfhi(w[u].w);
                va[4] += bflo(g2[u]);  va[5] += bfhi(g2[u]);
            }
        }
        for (; e < cnt; ++e) {
            int s = __shfl(myc, e, 64);
            const unsigned* rp = &nodeP[(size_t)s * 320 + lane5];
            uint4 w = *(const uint4*)rp;
            unsigned g2 = rp[4];
            float t = qv.x * bflo(w.x) + qv.y * bfhi(w.x);
            t += __shfl_xor(t, 1, 64);
            t += __shfl_xor(t, 2, 64);
            t += __shfl_xor(t, 4, 64);
            float a0 = t * 0.25f;
            float nm = fmaxf(m, a0);
            float sc = exp2f((m - nm) * L2E);
            float e0 = exp2f((a0 - nm) * L2E);
            d = d * sc + e0;
            ha0 = ha0 * sc + e0 * bflo(w.y);
            ha1 = ha1 * sc + e0 * bfhi(w.y);
            m = nm;
            va[0] += bflo(w.z); va[1] += bfhi(w.z);
            va[2] += bflo(w.w); va[3] += bfhi(w.w);
            va[4] += bflo(g2);  va[5] += bfhi(g2);
        }
    }
    float inv = (d > 0.f) ? 1.f / d : 0.f;
    float ox0 = ha0 * inv, ox1 = ha1 * inv;
    int cc0 = (lane & 7) * 2;
    float accq[6];
#pragma unroll
    for (int jj = 0; jj < 6; jj++) {
        int j = jj >> 1, c = cc0 + (jj & 1);
        accq[jj] = sbp[j * 16 + c];
    }
#pragma unroll
    for (int cp = 0; cp < 16; cp++) {
        int srcLane = (lane & 56) | (cp >> 1);
        float val = __shfl((cp & 1) ? ox1 : ox0, srcLane, 64);
#pragma unroll
        for (int jj = 0; jj < 6; jj++) {
            int j = jj >> 1, c = cc0 + (jj & 1);
            accq[jj] += val * sWp[cp * 48 + j * 16 + c];
        }
    }
    float2 vd2 = make_float2(0.f, 0.f);
#pragma unroll
    for (int s3 = 0; s3 < 3; s3++) {
        const float* vpr = &Cvp[((size_t)node * 3 + s3) * 384 + hh * 48];
        float2 p1 = *(const float2*)&vpr[c0];
        float2 p2 = *(const float2*)&vpr[16 + c0];
        vd2.x += p1.x * p2.x;
        vd2.y += p1.y * p2.y;
    }
    float2 hv = *(const float2*)&hin[(size_t)node * 128 + hc0];
    float2 o0;
    o0.x = hv.x + accq[2] + accq[4] * vd2.x;
    o0.y = hv.y + accq[3] + accq[5] * vd2.y;
    *(float2*)&out0[(size_t)node * 128 + hc0] = o0;
#pragma unroll
    for (int s3 = 0; s3 < 3; s3++) {
        float2 v3 = *(const float2*)&Cvp[((size_t)node * 3 + s3) * 384 + hh * 48 + 32 + c0];
        float2 vv = *(const float2*)&vecin[(size_t)node * 384 + s3 * 128 + hc0];
        float2 o1;
        o1.x = vv.x + v3.x * accq[0] + va[s3 * 2 + 0];
        o1.y = vv.y + v3.y * accq[1] + va[s3 * 2 + 1];
        *(float2*)&out1[(size_t)node * 384 + s3 * 128 + hc0] = o1;
    }
}

extern "C" void kernel_launch(void* const* d_in, const int* in_sizes, int n_in,
                              void* d_out, int out_size, void* d_ws, size_t ws_size,
                              hipStream_t stream) {
    const float* hin = (const float*)d_in[0];
    const float* vec = (const float*)d_in[1];
    const int* ei = (const int*)d_in[2];
    const float* Wq = (const float*)d_in[3];
    const float* bq = (const float*)d_in[4];
    const float* Wk = (const float*)d_in[5];
    const float* bk = (const float*)d_in[6];
    const float* Wv = (const float*)d_in[7];
    const float* bv = (const float*)d_in[8];
    const float* Wp = (const float*)d_in[9];
    const float* bp = (const float*)d_in[10];
    const float* Wvec = (const float*)d_in[11];

    int N = in_sizes[0] / 128;
    int E = in_sizes[2] / 2;
    float* out0 = (float*)d_out;
    float* out1 = out0 + (size_t)N * 128;

    float* wsf = (float*)d_ws;
    size_t off = 0;
    float* Cqkv = wsf + off; off += (size_t)N * 512;
    float* Cvp = wsf + off;  off += (size_t)N * 3 * 384;
    unsigned* nodeP = (unsigned*)(wsf + off); off += (size_t)N * 320;
    unsigned short* WBT = (unsigned short*)(wsf + off); off += (size_t)512 * 128 / 2;
    unsigned short* WVT = (unsigned short*)(wsf + off); off += (size_t)384 * 128 / 2;
    float* biasAll = wsf + off; off += 512;
    int* ip = (int*)(wsf + off);
    int* deg = ip;            ip += N;
    int* rowptr = ip;         ip += N + 1;
    int* cursor = ip;         ip += N;
    int* colb = ip;           ip += E;

    hipMemsetAsync(deg, 0, (size_t)N * sizeof(int), stream);
    hipLaunchKernelGGL(hist_kernel, dim3((E + 255) / 256), dim3(256), 0, stream, ei, deg, E);
    hipLaunchKernelGGL(scan_kernel, dim3(1), dim3(1024), 0, stream, deg, rowptr, cursor, N);
    hipLaunchKernelGGL(scatter_kernel, dim3((E + 255) / 256), dim3(256), 0, stream, ei, cursor, colb, E);
    hipLaunchKernelGGL(prep_kernel, dim3((512 * 128 + 384 * 128 + 512 + 255) / 256), dim3(256),
                       0, stream, Wq, Wk, Wv, Wvec, bq, bk, bv, WBT, WVT, biasAll);
    hipLaunchKernelGGL(gemm_mfma, dim3((N + 127) / 128, 4), dim3(256), 0, stream,
                       hin, WBT, biasAll, Cqkv, N, 512);
    hipLaunchKernelGGL(gemm_mfma, dim3((3 * N + 127) / 128, 3), dim3(256), 0, stream,
                       vec, WVT, (const float*)nullptr, Cvp, 3 * N, 384);
    hipLaunchKernelGGL(pack_kernel, dim3((N + 3) / 4), dim3(256), 0, stream,
                       Cqkv, vec, nodeP, N);
    hipLaunchKernelGGL(agg_kernel, dim3((N + 3) / 4), dim3(256), 0, stream,
                       rowptr, colb, Cqkv, Cvp, nodeP, hin, vec, Wp, bp, out0, out1, N);
}

// Round 5
// 284.947 us; speedup vs baseline: 2.8327x; 1.1612x over previous
//
#include <hip/hip_runtime.h>
#include <hip/hip_bf16.h>
#include <math.h>

// DecoderBlock: graph attention message passing.
// N=20000, HID=128, H=8, C=16, E=640000.
// r5: int8-quantized gather payload (640B/node row, per-node scales folded
// with 1/sqrt(C) and log2e), biased-u8 storage so unpack = v_cvt_f32_ubyte and
// the -128 correction is a single scalar accumulator per quantity.

typedef __attribute__((ext_vector_type(8))) short bf16x8;
typedef __attribute__((ext_vector_type(4))) float f32x4;

static __device__ inline unsigned f2bf(float x) {
    union { float f; unsigned u; } v; v.f = x;
    return (v.u + 0x7FFFu + ((v.u >> 16) & 1u)) >> 16;
}
static __device__ inline unsigned pack2(float a, float b) {
    return f2bf(a) | (f2bf(b) << 16);
}
static __device__ inline unsigned qb(float x) {
    return (unsigned)(__float2int_rn(x) + 128);
}
#define UB(w, i) ((float)(((w) >> (8 * (i))) & 0xffu))

__global__ __launch_bounds__(256) void hist_kernel(const int* __restrict__ ei,
                                                   int* __restrict__ deg, int E) {
    int i = blockIdx.x * 256 + threadIdx.x;
    if (i < E) atomicAdd(&deg[ei[E + i]], 1);
}

// Single block, 1024 threads, each owns 32 consecutive elements (n <= 32768).
__global__ __launch_bounds__(1024) void scan_kernel(const int* __restrict__ deg,
                                                    int* __restrict__ rowptr,
                                                    int* __restrict__ cursor, int n) {
    __shared__ int sh[1024];
    int tid = threadIdx.x;
    int base = tid * 32;
    int s = 0;
#pragma unroll
    for (int j = 0; j < 32; ++j) {
        int i = base + j;
        s += (i < n) ? deg[i] : 0;
    }
    sh[tid] = s;
    __syncthreads();
    for (int off = 1; off < 1024; off <<= 1) {
        int t = (tid >= off) ? sh[tid - off] : 0;
        __syncthreads();
        sh[tid] += t;
        __syncthreads();
    }
    int run = sh[tid] - s;
#pragma unroll
    for (int j = 0; j < 32; ++j) {
        int i = base + j;
        if (i < n) {
            int v = deg[i];
            cursor[i] = run;
            run += v;
            rowptr[i + 1] = run;
        }
    }
    if (tid == 0) rowptr[0] = 0;
}

__global__ __launch_bounds__(256) void scatter_kernel(const int* __restrict__ ei,
                                                      int* __restrict__ cursor,
                                                      int* __restrict__ colb, int E) {
    int i = blockIdx.x * 256 + threadIdx.x;
    if (i < E) {
        int d = ei[E + i];
        int pos = atomicAdd(&cursor[d], 1);
        colb[pos] = ei[i];
    }
}

// WBT[512][128] bf16: col-major-of-[Wq|Wk|Wv]; WVT[384][128] bf16: Wvec^T;
// biasAll[512] f32.
__global__ __launch_bounds__(256) void prep_kernel(const float* __restrict__ Wq,
                                                   const float* __restrict__ Wk,
                                                   const float* __restrict__ Wv,
                                                   const float* __restrict__ Wvec,
                                                   const float* __restrict__ bq,
                                                   const float* __restrict__ bk,
                                                   const float* __restrict__ bv,
                                                   unsigned short* __restrict__ WBT,
                                                   unsigned short* __restrict__ WVT,
                                                   float* __restrict__ biasAll) {
    int idx = blockIdx.x * 256 + threadIdx.x;
    if (idx < 512 * 128) {
        int c = idx >> 7, k = idx & 127;
        float v;
        if (c < 128) v = Wq[k * 128 + c];
        else if (c < 256) v = Wk[k * 128 + (c - 128)];
        else v = Wv[k * 256 + (c - 256)];
        WBT[idx] = (unsigned short)f2bf(v);
    } else if (idx < 512 * 128 + 384 * 128) {
        int j = idx - 512 * 128;
        int c = j >> 7, k = j & 127;
        WVT[j] = (unsigned short)f2bf(Wvec[k * 384 + c]);
    } else if (idx < 512 * 128 + 384 * 128 + 512) {
        int c = idx - (512 * 128 + 384 * 128);
        biasAll[c] = (c < 128) ? bq[c] : (c < 256) ? bk[c - 128] : bv[c - 256];
    }
}

// C[M][ldc] = A[M][128](f32,cvt->bf16) @ B[128][ldc](bf16, given as BT[col][k]).
// 128x128 tile, K=128 in one shot. 4 waves, each 64x64 (4x4 frags of 16x16x32).
__global__ __launch_bounds__(256) void gemm_mfma(const float* __restrict__ A,
                                                 const unsigned short* __restrict__ BT,
                                                 const float* __restrict__ bias,
                                                 float* __restrict__ C, int M, int ldc) {
    __shared__ unsigned short sA[128 * 136];
    __shared__ unsigned short sB[128 * 136];
    int tid = threadIdx.x;
    int row0 = blockIdx.x * 128, col0 = blockIdx.y * 128;
#pragma unroll
    for (int i = 0; i < 8; ++i) {
        int id = tid + i * 256;        // 0..2047
        int r = id >> 4, cof = id & 15;
        uint4 wa = make_uint4(0u, 0u, 0u, 0u);
        int grow = row0 + r;
        if (grow < M) {
            const float* ap = &A[(size_t)grow * 128 + cof * 8];
            float4 x0 = *(const float4*)ap;
            float4 x1 = *(const float4*)(ap + 4);
            wa.x = pack2(x0.x, x0.y); wa.y = pack2(x0.z, x0.w);
            wa.z = pack2(x1.x, x1.y); wa.w = pack2(x1.z, x1.w);
        }
        *(uint4*)&sA[r * 136 + cof * 8] = wa;
        uint4 wb = *(const uint4*)&BT[((size_t)(col0 + r)) * 128 + cof * 8];
        *(uint4*)&sB[r * 136 + cof * 8] = wb;
    }
    __syncthreads();
    int wid = tid >> 6, lane = tid & 63;
    int wr = (wid >> 1) * 64, wc = (wid & 1) * 64;
    int lr = lane & 15, lk = lane >> 4;
    f32x4 acc[4][4] = {};
#pragma unroll
    for (int ks = 0; ks < 4; ++ks) {
        bf16x8 af[4], bfr[4];
#pragma unroll
        for (int mm = 0; mm < 4; ++mm)
            af[mm] = *(const bf16x8*)&sA[(wr + mm * 16 + lr) * 136 + ks * 32 + lk * 8];
#pragma unroll
        for (int nn = 0; nn < 4; ++nn)
            bfr[nn] = *(const bf16x8*)&sB[(wc + nn * 16 + lr) * 136 + ks * 32 + lk * 8];
#pragma unroll
        for (int mm = 0; mm < 4; ++mm)
#pragma unroll
            for (int nn = 0; nn < 4; ++nn)
                acc[mm][nn] = __builtin_amdgcn_mfma_f32_16x16x32_bf16(af[mm], bfr[nn],
                                                                     acc[mm][nn], 0, 0, 0);
    }
#pragma unroll
    for (int mm = 0; mm < 4; ++mm) {
#pragma unroll
        for (int r4 = 0; r4 < 4; ++r4) {
            int row = row0 + wr + mm * 16 + lk * 4 + r4;
            if (row >= M) continue;
#pragma unroll
            for (int nn = 0; nn < 4; ++nn) {
                int col = col0 + wc + nn * 16 + lr;
                float v = acc[mm][nn][r4];
                if (bias) v += bias[col];
                C[(size_t)row * ldc + col] = v;
            }
        }
    }
}

// int8 gather row, 640B = 160 uints:
//  [0..255]   lane's uint {k0,k1,v0,v1} biased u8
//  [256..511] lane's uint {f00,f01,f10,f11}
//  [512..639] lane's ushort {f20,f21}
// scales4[n] = {kmax*0.25*log2e/127, vmax/127, fmax/127, 0}
__global__ __launch_bounds__(256) void pack_kernel(const float* __restrict__ Cqkv,
                                                   const float* __restrict__ vec,
                                                   unsigned* __restrict__ nodeP,
                                                   float4* __restrict__ scales4, int n) {
    int lane = threadIdx.x & 63;
    int node = blockIdx.x * 4 + (threadIdx.x >> 6);
    if (node >= n) return;
    int hc0 = lane * 2, hh = lane >> 3, c0 = hc0 & 15;
    const float* row = &Cqkv[(size_t)node * 512];
    float2 kk = *(const float2*)&row[128 + hc0];
    float2 v0 = *(const float2*)&row[256 + hh * 32 + c0];
    float2 s1 = *(const float2*)&row[256 + hh * 32 + 16 + c0];
    float2 a0 = *(const float2*)&vec[(size_t)node * 384 + 0 * 128 + hc0];
    float2 a1 = *(const float2*)&vec[(size_t)node * 384 + 1 * 128 + hc0];
    float2 a2 = *(const float2*)&vec[(size_t)node * 384 + 2 * 128 + hc0];
    float f00 = a0.x * s1.x, f01 = a0.y * s1.y;
    float f10 = a1.x * s1.x, f11 = a1.y * s1.y;
    float f20 = a2.x * s1.x, f21 = a2.y * s1.y;
    float km = fmaxf(fabsf(kk.x), fabsf(kk.y));
    float vm = fmaxf(fabsf(v0.x), fabsf(v0.y));
    float fm = fmaxf(fmaxf(fmaxf(fabsf(f00), fabsf(f01)), fmaxf(fabsf(f10), fabsf(f11))),
                     fmaxf(fabsf(f20), fabsf(f21)));
#pragma unroll
    for (int off = 1; off < 64; off <<= 1) {
        km = fmaxf(km, __shfl_xor(km, off, 64));
        vm = fmaxf(vm, __shfl_xor(vm, off, 64));
        fm = fmaxf(fm, __shfl_xor(fm, off, 64));
    }
    km = fmaxf(km, 1e-20f);
    vm = fmaxf(vm, 1e-20f);
    fm = fmaxf(fm, 1e-20f);
    float ki = 127.f / km, vi = 127.f / vm, fi = 127.f / fm;
    unsigned kvw = qb(kk.x * ki) | (qb(kk.y * ki) << 8) | (qb(v0.x * vi) << 16) |
                   (qb(v0.y * vi) << 24);
    unsigned fAw = qb(f00 * fi) | (qb(f01 * fi) << 8) | (qb(f10 * fi) << 16) |
                   (qb(f11 * fi) << 24);
    unsigned short fCw = (unsigned short)(qb(f20 * fi) | (qb(f21 * fi) << 8));
    unsigned* rp = nodeP + (size_t)node * 160;
    rp[lane] = kvw;
    rp[64 + lane] = fAw;
    ((unsigned short*)rp)[256 + lane] = fCw;
    if (lane == 0)
        scales4[node] = make_float4(km * (0.25f * 1.44269504088896f / 127.f),
                                    vm * (1.f / 127.f), fm * (1.f / 127.f), 0.f);
}

// One wave per dst node; 4 waves per block. lane -> channels {2*lane, 2*lane+1}.
__global__ __launch_bounds__(256) void agg_kernel(
    const int* __restrict__ rowptr, const int* __restrict__ colb,
    const float* __restrict__ Cqkv, const float* __restrict__ Cvp,
    const unsigned* __restrict__ nodeP, const float4* __restrict__ scales4,
    const float* __restrict__ hin, const float* __restrict__ vecin,
    const float* __restrict__ Wp, const float* __restrict__ bp,
    float* __restrict__ out0, float* __restrict__ out1, int n) {
    __shared__ float sWp[768];
    __shared__ float sbp[48];
    for (int i = threadIdx.x; i < 768; i += 256) sWp[i] = Wp[i];
    for (int i = threadIdx.x; i < 48; i += 256) sbp[i] = bp[i];
    __syncthreads();
    int lane = threadIdx.x & 63;
    int node = blockIdx.x * 4 + (threadIdx.x >> 6);
    if (node >= n) return;
    int beg = rowptr[node], end = rowptr[node + 1];
    int hc0 = lane * 2;
    int hh = lane >> 3, c0 = hc0 & 15;
    int lane4 = lane * 4, lane2 = lane * 2;
    float2 qv = *(const float2*)&Cqkv[(size_t)node * 512 + hc0];
    // Qs: sum of q over this head's 16 channels (for the -128 bias correction)
    float qs = qv.x + qv.y;
    qs += __shfl_xor(qs, 1, 64);
    qs += __shfl_xor(qs, 2, 64);
    qs += __shfl_xor(qs, 4, 64);
    float c0q = 128.f * qs;
    float m = -INFINITY, d = 0.f, ha0 = 0.f, ha1 = 0.f, esum = 0.f, fsS = 0.f;
    float va[6] = {0.f, 0.f, 0.f, 0.f, 0.f, 0.f};
    for (int base = beg; base < end; base += 64) {
        int cnt = end - base;
        if (cnt > 64) cnt = 64;
        int myc = (lane < cnt) ? colb[base + lane] : 0;
        int e = 0;
        for (; e + 3 < cnt; e += 4) {
            unsigned kv[4], fA[4]; unsigned fC[4]; float4 sc4[4];
#pragma unroll
            for (int u = 0; u < 4; ++u) {
                int s = __shfl(myc, e + u, 64);
                const char* rb = (const char*)nodeP + (size_t)s * 640;
                kv[u] = *(const unsigned*)(rb + lane4);
                fA[u] = *(const unsigned*)(rb + 256 + lane4);
                fC[u] = *(const unsigned short*)(rb + 512 + lane2);
                sc4[u] = scales4[s];
            }
            float p[4];
#pragma unroll
            for (int u = 0; u < 4; ++u) {
                float t = qv.x * UB(kv[u], 0) + qv.y * UB(kv[u], 1);
                t += __shfl_xor(t, 1, 64);
                t += __shfl_xor(t, 2, 64);
                t += __shfl_xor(t, 4, 64);
                p[u] = sc4[u].x * (t - c0q);   // log2-domain alpha
            }
            float nm = fmaxf(fmaxf(fmaxf(p[0], p[1]), fmaxf(p[2], p[3])), m);
            float scm = exp2f(m - nm);
            float dsum = 0.f, h0 = 0.f, h1 = 0.f, es = 0.f;
#pragma unroll
            for (int u = 0; u < 4; ++u) {
                float ew = exp2f(p[u] - nm);
                dsum += ew;
                float evs = ew * sc4[u].y;
                h0 += evs * UB(kv[u], 2);
                h1 += evs * UB(kv[u], 3);
                es += evs;
            }
            d = d * scm + dsum;
            ha0 = ha0 * scm + h0;
            ha1 = ha1 * scm + h1;
            esum = esum * scm + es;
            m = nm;
#pragma unroll
            for (int u = 0; u < 4; ++u) {
                float fs = sc4[u].z;
                va[0] += fs * UB(fA[u], 0);
                va[1] += fs * UB(fA[u], 1);
                va[2] += fs * UB(fA[u], 2);
                va[3] += fs * UB(fA[u], 3);
                va[4] += fs * UB(fC[u], 0);
                va[5] += fs * UB(fC[u], 1);
                fsS += fs;
            }
        }
        for (; e < cnt; ++e) {
            int s = __shfl(myc, e, 64);
            const char* rb = (const char*)nodeP + (size_t)s * 640;
            unsigned kv = *(const unsigned*)(rb + lane4);
            unsigned fA = *(const unsigned*)(rb + 256 + lane4);
            unsigned fC = *(const unsigned short*)(rb + 512 + lane2);
            float4 sc4 = scales4[s];
            float t = qv.x * UB(kv, 0) + qv.y * UB(kv, 1);
            t += __shfl_xor(t, 1, 64);
            t += __shfl_xor(t, 2, 64);
            t += __shfl_xor(t, 4, 64);
            float p = sc4.x * (t - c0q);
            float nm = fmaxf(m, p);
            float scm = exp2f(m - nm);
            float ew = exp2f(p - nm);
            float evs = ew * sc4.y;
            d = d * scm + ew;
            ha0 = ha0 * scm + evs * UB(kv, 2);
            ha1 = ha1 * scm + evs * UB(kv, 3);
            esum = esum * scm + evs;
            m = nm;
            float fs = sc4.z;
            va[0] += fs * UB(fA, 0);
            va[1] += fs * UB(fA, 1);
            va[2] += fs * UB(fA, 2);
            va[3] += fs * UB(fA, 3);
            va[4] += fs * UB(fC, 0);
            va[5] += fs * UB(fC, 1);
            fsS += fs;
        }
    }
    float inv = (d > 0.f) ? 1.f / d : 0.f;
    float corr = 128.f * esum;
    float ox0 = (ha0 - corr) * inv, ox1 = (ha1 - corr) * inv;
    float fcor = 128.f * fsS;
#pragma unroll
    for (int j = 0; j < 6; ++j) va[j] -= fcor;
    int cc0 = (lane & 7) * 2;
    float accq[6];
#pragma unroll
    for (int jj = 0; jj < 6; jj++) {
        int j = jj >> 1, c = cc0 + (jj & 1);
        accq[jj] = sbp[j * 16 + c];
    }
#pragma unroll
    for (int cp = 0; cp < 16; cp++) {
        int srcLane = (lane & 56) | (cp >> 1);
        float val = __shfl((cp & 1) ? ox1 : ox0, srcLane, 64);
#pragma unroll
        for (int jj = 0; jj < 6; jj++) {
            int j = jj >> 1, c = cc0 + (jj & 1);
            accq[jj] += val * sWp[cp * 48 + j * 16 + c];
        }
    }
    float2 vd2 = make_float2(0.f, 0.f);
#pragma unroll
    for (int s3 = 0; s3 < 3; s3++) {
        const float* vpr = &Cvp[((size_t)node * 3 + s3) * 384 + hh * 48];
        float2 p1 = *(const float2*)&vpr[c0];
        float2 p2 = *(const float2*)&vpr[16 + c0];
        vd2.x += p1.x * p2.x;
        vd2.y += p1.y * p2.y;
    }
    float2 hv = *(const float2*)&hin[(size_t)node * 128 + hc0];
    float2 o0;
    o0.x = hv.x + accq[2] + accq[4] * vd2.x;
    o0.y = hv.y + accq[3] + accq[5] * vd2.y;
    *(float2*)&out0[(size_t)node * 128 + hc0] = o0;
#pragma unroll
    for (int s3 = 0; s3 < 3; s3++) {
        float2 v3 = *(const float2*)&Cvp[((size_t)node * 3 + s3) * 384 + hh * 48 + 32 + c0];
        float2 vv = *(const float2*)&vecin[(size_t)node * 384 + s3 * 128 + hc0];
        float2 o1;
        o1.x = vv.x + v3.x * accq[0] + va[s3 * 2 + 0];
        o1.y = vv.y + v3.y * accq[1] + va[s3 * 2 + 1];
        *(float2*)&out1[(size_t)node * 384 + s3 * 128 + hc0] = o1;
    }
}

extern "C" void kernel_launch(void* const* d_in, const int* in_sizes, int n_in,
                              void* d_out, int out_size, void* d_ws, size_t ws_size,
                              hipStream_t stream) {
    const float* hin = (const float*)d_in[0];
    const float* vec = (const float*)d_in[1];
    const int* ei = (const int*)d_in[2];
    const float* Wq = (const float*)d_in[3];
    const float* bq = (const float*)d_in[4];
    const float* Wk = (const float*)d_in[5];
    const float* bk = (const float*)d_in[6];
    const float* Wv = (const float*)d_in[7];
    const float* bv = (const float*)d_in[8];
    const float* Wp = (const float*)d_in[9];
    const float* bp = (const float*)d_in[10];
    const float* Wvec = (const float*)d_in[11];

    int N = in_sizes[0] / 128;
    int E = in_sizes[2] / 2;
    float* out0 = (float*)d_out;
    float* out1 = out0 + (size_t)N * 128;

    float* wsf = (float*)d_ws;
    size_t off = 0;
    float* Cqkv = wsf + off; off += (size_t)N * 512;
    float* Cvp = wsf + off;  off += (size_t)N * 3 * 384;
    unsigned* nodeP = (unsigned*)(wsf + off); off += (size_t)N * 160;
    float4* scales4 = (float4*)(wsf + off); off += (size_t)N * 4;
    unsigned short* WBT = (unsigned short*)(wsf + off); off += (size_t)512 * 128 / 2;
    unsigned short* WVT = (unsigned short*)(wsf + off); off += (size_t)384 * 128 / 2;
    float* biasAll = wsf + off; off += 512;
    int* ip = (int*)(wsf + off);
    int* deg = ip;            ip += N;
    int* rowptr = ip;         ip += N + 1;
    int* cursor = ip;         ip += N;
    int* colb = ip;           ip += E;

    hipMemsetAsync(deg, 0, (size_t)N * sizeof(int), stream);
    hipLaunchKernelGGL(hist_kernel, dim3((E + 255) / 256), dim3(256), 0, stream, ei, deg, E);
    hipLaunchKernelGGL(scan_kernel, dim3(1), dim3(1024), 0, stream, deg, rowptr, cursor, N);
    hipLaunchKernelGGL(scatter_kernel, dim3((E + 255) / 256), dim3(256), 0, stream, ei, cursor, colb, E);
    hipLaunchKernelGGL(prep_kernel, dim3((512 * 128 + 384 * 128 + 512 + 255) / 256), dim3(256),
                       0, stream, Wq, Wk, Wv, Wvec, bq, bk, bv, WBT, WVT, biasAll);
    hipLaunchKernelGGL(gemm_mfma, dim3((N + 127) / 128, 4), dim3(256), 0, stream,
                       hin, WBT, biasAll, Cqkv, N, 512);
    hipLaunchKernelGGL(gemm_mfma, dim3((3 * N + 127) / 128, 3), dim3(256), 0, stream,
                       vec, WVT, (const float*)nullptr, Cvp, 3 * N, 384);
    hipLaunchKernelGGL(pack_kernel, dim3((N + 3) / 4), dim3(256), 0, stream,
                       Cqkv, vec, nodeP, scales4, N);
    hipLaunchKernelGGL(agg_kernel, dim3((N + 3) / 4), dim3(256), 0, stream,
                       rowptr, colb, Cqkv, Cvp, nodeP, scales4, hin, vec, Wp, bp, out0, out1, N);
}

// Round 6
// 254.794 us; speedup vs baseline: 3.1679x; 1.1183x over previous
//
#include <hip/hip_runtime.h>
#include <hip/hip_bf16.h>
#include <math.h>

// DecoderBlock: graph attention message passing.
// N=20000, HID=128, H=8, C=16, E=640000.
// r6: agg edge loop scalarized (readlane -> SGPR row base, SALU addressing,
// loop-invariant voffsets), single 656B/node payload row
// [scales 16B | kv+fA 8B/lane | fC 2B/lane]; coalesced scan; vectorized
// hist/scatter; hist+prep merged; pack merged into gemm_vec launch.

typedef __attribute__((ext_vector_type(8))) short bf16x8;
typedef __attribute__((ext_vector_type(4))) float f32x4;

#define ROWB 656  // 16 + 64*8 + 64*2

static __device__ inline unsigned f2bf(float x) {
    union { float f; unsigned u; } v; v.f = x;
    return (v.u + 0x7FFFu + ((v.u >> 16) & 1u)) >> 16;
}
static __device__ inline unsigned pack2(float a, float b) {
    return f2bf(a) | (f2bf(b) << 16);
}
static __device__ inline unsigned qb(float x) {
    return (unsigned)(__float2int_rn(x) + 128);
}
#define UB(w, i) ((float)(((w) >> (8 * (i))) & 0xffu))

// ---- hist + prep merged ------------------------------------------------
__global__ __launch_bounds__(256) void hist_prep_kernel(
    const int* __restrict__ ei, int* __restrict__ deg, int E,
    const float* __restrict__ Wq, const float* __restrict__ Wk,
    const float* __restrict__ Wv, const float* __restrict__ Wvec,
    const float* __restrict__ bq, const float* __restrict__ bk,
    const float* __restrict__ bv,
    unsigned short* __restrict__ WBT, unsigned short* __restrict__ WVT,
    float* __restrict__ biasAll, int histBlocks) {
    if (blockIdx.x < (unsigned)histBlocks) {
        int i4 = (blockIdx.x * 256 + threadIdx.x) * 4;
        if (i4 + 3 < E) {
            int4 d4 = *(const int4*)&ei[E + i4];
            atomicAdd(&deg[d4.x], 1);
            atomicAdd(&deg[d4.y], 1);
            atomicAdd(&deg[d4.z], 1);
            atomicAdd(&deg[d4.w], 1);
        } else {
            for (int i = i4; i < E; ++i) atomicAdd(&deg[ei[E + i]], 1);
        }
        return;
    }
    int idx = (blockIdx.x - histBlocks) * 256 + threadIdx.x;
    if (idx < 512 * 128) {
        int c = idx >> 7, k = idx & 127;
        float v;
        if (c < 128) v = Wq[k * 128 + c];
        else if (c < 256) v = Wk[k * 128 + (c - 128)];
        else v = Wv[k * 256 + (c - 256)];
        WBT[idx] = (unsigned short)f2bf(v);
    } else if (idx < 512 * 128 + 384 * 128) {
        int j = idx - 512 * 128;
        int c = j >> 7, k = j & 127;
        WVT[j] = (unsigned short)f2bf(Wvec[k * 384 + c]);
    } else if (idx < 512 * 128 + 384 * 128 + 512) {
        int c = idx - (512 * 128 + 384 * 128);
        biasAll[c] = (c < 128) ? bq[c] : (c < 256) ? bk[c - 128] : bv[c - 256];
    }
}

// ---- scan: single block, 1024 threads, 20 elems/thread, int4 loads -----
__global__ __launch_bounds__(1024) void scan_kernel(const int* __restrict__ deg,
                                                    int* __restrict__ rowptr,
                                                    int* __restrict__ cursor, int n) {
    __shared__ int sh[1024];
    int tid = threadIdx.x;
    int base = tid * 20;
    int v[20];
    int s = 0;
#pragma unroll
    for (int j4 = 0; j4 < 5; ++j4) {
        int4 w;
        if (base + j4 * 4 + 3 < n) {
            w = *(const int4*)&deg[base + j4 * 4];
        } else {
            int t[4];
#pragma unroll
            for (int k = 0; k < 4; ++k) {
                int i = base + j4 * 4 + k;
                t[k] = (i < n) ? deg[i] : 0;
            }
            w = make_int4(t[0], t[1], t[2], t[3]);
        }
        v[j4 * 4 + 0] = w.x; v[j4 * 4 + 1] = w.y;
        v[j4 * 4 + 2] = w.z; v[j4 * 4 + 3] = w.w;
        s += w.x + w.y + w.z + w.w;
    }
    sh[tid] = s;
    __syncthreads();
    for (int off = 1; off < 1024; off <<= 1) {
        int t = (tid >= off) ? sh[tid - off] : 0;
        __syncthreads();
        sh[tid] += t;
        __syncthreads();
    }
    int run = sh[tid] - s;
#pragma unroll
    for (int j = 0; j < 20; ++j) {
        int i = base + j;
        if (i < n) {
            cursor[i] = run;
            run += v[j];
            rowptr[i + 1] = run;
        }
    }
    if (tid == 0) rowptr[0] = 0;
}

__global__ __launch_bounds__(256) void scatter_kernel(const int* __restrict__ ei,
                                                      int* __restrict__ cursor,
                                                      int* __restrict__ colb, int E) {
    int i4 = (blockIdx.x * 256 + threadIdx.x) * 4;
    if (i4 + 3 < E) {
        int4 s4 = *(const int4*)&ei[i4];
        int4 d4 = *(const int4*)&ei[E + i4];
        colb[atomicAdd(&cursor[d4.x], 1)] = s4.x;
        colb[atomicAdd(&cursor[d4.y], 1)] = s4.y;
        colb[atomicAdd(&cursor[d4.z], 1)] = s4.z;
        colb[atomicAdd(&cursor[d4.w], 1)] = s4.w;
    } else {
        for (int i = i4; i < E; ++i)
            colb[atomicAdd(&cursor[ei[E + i]], 1)] = ei[i];
    }
}

// ---- MFMA GEMM (unchanged from r5) -------------------------------------
__global__ __launch_bounds__(256) void gemm_mfma(const float* __restrict__ A,
                                                 const unsigned short* __restrict__ BT,
                                                 const float* __restrict__ bias,
                                                 float* __restrict__ C, int M, int ldc) {
    __shared__ unsigned short sA[128 * 136];
    __shared__ unsigned short sB[128 * 136];
    int tid = threadIdx.x;
    int row0 = blockIdx.x * 128, col0 = blockIdx.y * 128;
#pragma unroll
    for (int i = 0; i < 8; ++i) {
        int id = tid + i * 256;
        int r = id >> 4, cof = id & 15;
        uint4 wa = make_uint4(0u, 0u, 0u, 0u);
        int grow = row0 + r;
        if (grow < M) {
            const float* ap = &A[(size_t)grow * 128 + cof * 8];
            float4 x0 = *(const float4*)ap;
            float4 x1 = *(const float4*)(ap + 4);
            wa.x = pack2(x0.x, x0.y); wa.y = pack2(x0.z, x0.w);
            wa.z = pack2(x1.x, x1.y); wa.w = pack2(x1.z, x1.w);
        }
        *(uint4*)&sA[r * 136 + cof * 8] = wa;
        uint4 wb = *(const uint4*)&BT[((size_t)(col0 + r)) * 128 + cof * 8];
        *(uint4*)&sB[r * 136 + cof * 8] = wb;
    }
    __syncthreads();
    int wid = tid >> 6, lane = tid & 63;
    int wr = (wid >> 1) * 64, wc = (wid & 1) * 64;
    int lr = lane & 15, lk = lane >> 4;
    f32x4 acc[4][4] = {};
#pragma unroll
    for (int ks = 0; ks < 4; ++ks) {
        bf16x8 af[4], bfr[4];
#pragma unroll
        for (int mm = 0; mm < 4; ++mm)
            af[mm] = *(const bf16x8*)&sA[(wr + mm * 16 + lr) * 136 + ks * 32 + lk * 8];
#pragma unroll
        for (int nn = 0; nn < 4; ++nn)
            bfr[nn] = *(const bf16x8*)&sB[(wc + nn * 16 + lr) * 136 + ks * 32 + lk * 8];
#pragma unroll
        for (int mm = 0; mm < 4; ++mm)
#pragma unroll
            for (int nn = 0; nn < 4; ++nn)
                acc[mm][nn] = __builtin_amdgcn_mfma_f32_16x16x32_bf16(af[mm], bfr[nn],
                                                                     acc[mm][nn], 0, 0, 0);
    }
#pragma unroll
    for (int mm = 0; mm < 4; ++mm) {
#pragma unroll
        for (int r4 = 0; r4 < 4; ++r4) {
            int row = row0 + wr + mm * 16 + lk * 4 + r4;
            if (row >= M) continue;
#pragma unroll
            for (int nn = 0; nn < 4; ++nn) {
                int col = col0 + wc + nn * 16 + lr;
                float v = acc[mm][nn][r4];
                if (bias) v += bias[col];
                C[(size_t)row * ldc + col] = v;
            }
        }
    }
}

// ---- pack body (device fn) ---------------------------------------------
// row layout (ROWB=656): [0..15] float4 {kscale, vscale, fscale, 0}
//   [16 + lane*8]  uint2 {kv, fA}   kv={k0,k1,v0,v1}, fA={f00,f01,f10,f11}
//   [528 + lane*2] ushort fC = {f20,f21}
static __device__ void pack_body(const float* __restrict__ Cqkv,
                                 const float* __restrict__ vec,
                                 char* __restrict__ nodeP, int node, int lane, int n) {
    if (node >= n) return;
    int hc0 = lane * 2, hh = lane >> 3, c0 = hc0 & 15;
    const float* row = &Cqkv[(size_t)node * 512];
    float2 kk = *(const float2*)&row[128 + hc0];
    float2 v0 = *(const float2*)&row[256 + hh * 32 + c0];
    float2 s1 = *(const float2*)&row[256 + hh * 32 + 16 + c0];
    float2 a0 = *(const float2*)&vec[(size_t)node * 384 + 0 * 128 + hc0];
    float2 a1 = *(const float2*)&vec[(size_t)node * 384 + 1 * 128 + hc0];
    float2 a2 = *(const float2*)&vec[(size_t)node * 384 + 2 * 128 + hc0];
    float f00 = a0.x * s1.x, f01 = a0.y * s1.y;
    float f10 = a1.x * s1.x, f11 = a1.y * s1.y;
    float f20 = a2.x * s1.x, f21 = a2.y * s1.y;
    float km = fmaxf(fabsf(kk.x), fabsf(kk.y));
    float vm = fmaxf(fabsf(v0.x), fabsf(v0.y));
    float fm = fmaxf(fmaxf(fmaxf(fabsf(f00), fabsf(f01)), fmaxf(fabsf(f10), fabsf(f11))),
                     fmaxf(fabsf(f20), fabsf(f21)));
#pragma unroll
    for (int off = 1; off < 64; off <<= 1) {
        km = fmaxf(km, __shfl_xor(km, off, 64));
        vm = fmaxf(vm, __shfl_xor(vm, off, 64));
        fm = fmaxf(fm, __shfl_xor(fm, off, 64));
    }
    km = fmaxf(km, 1e-20f);
    vm = fmaxf(vm, 1e-20f);
    fm = fmaxf(fm, 1e-20f);
    float ki = 127.f / km, vi = 127.f / vm, fi = 127.f / fm;
    unsigned kvw = qb(kk.x * ki) | (qb(kk.y * ki) << 8) | (qb(v0.x * vi) << 16) |
                   (qb(v0.y * vi) << 24);
    unsigned fAw = qb(f00 * fi) | (qb(f01 * fi) << 8) | (qb(f10 * fi) << 16) |
                   (qb(f11 * fi) << 24);
    unsigned short fCw = (unsigned short)(qb(f20 * fi) | (qb(f21 * fi) << 8));
    char* rp = nodeP + (size_t)node * ROWB;
    *(uint2*)(rp + 16 + lane * 8) = make_uint2(kvw, fAw);
    *(unsigned short*)(rp + 528 + lane * 2) = fCw;
    if (lane == 0)
        *(float4*)rp = make_float4(km * (0.25f * 1.44269504088896f / 127.f),
                                   vm * (1.f / 127.f), fm * (1.f / 127.f), 0.f);
}

// ---- gemm_vec + pack merged launch -------------------------------------
__global__ __launch_bounds__(256) void gemmvec_pack_kernel(
    const float* __restrict__ vec, const unsigned short* __restrict__ WVT,
    float* __restrict__ Cvp, int Mv, int gemmBlocksX, int gemmBlocks,
    const float* __restrict__ Cqkv, char* __restrict__ nodeP, int n) {
    if (blockIdx.x < (unsigned)gemmBlocks) {
        // re-dispatch as 2D
        int bx = blockIdx.x % gemmBlocksX;
        int by = blockIdx.x / gemmBlocksX;
        // inline gemm_mfma with row0 = bx*128, col0 = by*128, ldc=384, no bias
        __shared__ unsigned short sA[128 * 136];
        __shared__ unsigned short sB[128 * 136];
        int tid = threadIdx.x;
        int row0 = bx * 128, col0 = by * 128;
#pragma unroll
        for (int i = 0; i < 8; ++i) {
            int id = tid + i * 256;
            int r = id >> 4, cof = id & 15;
            uint4 wa = make_uint4(0u, 0u, 0u, 0u);
            int grow = row0 + r;
            if (grow < Mv) {
                const float* ap = &vec[(size_t)grow * 128 + cof * 8];
                float4 x0 = *(const float4*)ap;
                float4 x1 = *(const float4*)(ap + 4);
                wa.x = pack2(x0.x, x0.y); wa.y = pack2(x0.z, x0.w);
                wa.z = pack2(x1.x, x1.y); wa.w = pack2(x1.z, x1.w);
            }
            *(uint4*)&sA[r * 136 + cof * 8] = wa;
            uint4 wb = *(const uint4*)&WVT[((size_t)(col0 + r)) * 128 + cof * 8];
            *(uint4*)&sB[r * 136 + cof * 8] = wb;
        }
        __syncthreads();
        int wid = tid >> 6, lane = tid & 63;
        int wr = (wid >> 1) * 64, wc = (wid & 1) * 64;
        int lr = lane & 15, lk = lane >> 4;
        f32x4 acc[4][4] = {};
#pragma unroll
        for (int ks = 0; ks < 4; ++ks) {
            bf16x8 af[4], bfr[4];
#pragma unroll
            for (int mm = 0; mm < 4; ++mm)
                af[mm] = *(const bf16x8*)&sA[(wr + mm * 16 + lr) * 136 + ks * 32 + lk * 8];
#pragma unroll
            for (int nn = 0; nn < 4; ++nn)
                bfr[nn] = *(const bf16x8*)&sB[(wc + nn * 16 + lr) * 136 + ks * 32 + lk * 8];
#pragma unroll
            for (int mm = 0; mm < 4; ++mm)
#pragma unroll
                for (int nn = 0; nn < 4; ++nn)
                    acc[mm][nn] = __builtin_amdgcn_mfma_f32_16x16x32_bf16(af[mm], bfr[nn],
                                                                         acc[mm][nn], 0, 0, 0);
        }
#pragma unroll
        for (int mm = 0; mm < 4; ++mm) {
#pragma unroll
            for (int r4 = 0; r4 < 4; ++r4) {
                int row = row0 + wr + mm * 16 + lk * 4 + r4;
                if (row >= Mv) continue;
#pragma unroll
                for (int nn = 0; nn < 4; ++nn) {
                    int col = col0 + wc + nn * 16 + lr;
                    Cvp[(size_t)row * 384 + col] = acc[mm][nn][r4];
                }
            }
        }
    } else {
        int pid = blockIdx.x - gemmBlocks;
        int lane = threadIdx.x & 63;
        int node = pid * 4 + (threadIdx.x >> 6);
        pack_body(Cqkv, vec, nodeP, node, lane, n);
    }
}

// ---- agg: scalarized edge loop -----------------------------------------
__global__ __launch_bounds__(256) void agg_kernel(
    const int* __restrict__ rowptr, const int* __restrict__ colb,
    const float* __restrict__ Cqkv, const float* __restrict__ Cvp,
    const char* __restrict__ nodeP,
    const float* __restrict__ hin, const float* __restrict__ vecin,
    const float* __restrict__ Wp, const float* __restrict__ bp,
    float* __restrict__ out0, float* __restrict__ out1, int n) {
    __shared__ float sWp[768];
    __shared__ float sbp[48];
    for (int i = threadIdx.x; i < 768; i += 256) sWp[i] = Wp[i];
    for (int i = threadIdx.x; i < 48; i += 256) sbp[i] = bp[i];
    __syncthreads();
    int lane = threadIdx.x & 63;
    int node = blockIdx.x * 4 + (threadIdx.x >> 6);
    if (node >= n) return;
    int beg = rowptr[node], end = rowptr[node + 1];
    int hc0 = lane * 2;
    int hh = lane >> 3, c0 = hc0 & 15;
    int off8 = 16 + lane * 8;   // loop-invariant voffsets
    int off2 = 528 + lane * 2;
    float2 qv = *(const float2*)&Cqkv[(size_t)node * 512 + hc0];
    float qs = qv.x + qv.y;
    qs += __shfl_xor(qs, 1, 64);
    qs += __shfl_xor(qs, 2, 64);
    qs += __shfl_xor(qs, 4, 64);
    float c0q = 128.f * qs;
    float m = -INFINITY, d = 0.f, ha0 = 0.f, ha1 = 0.f, esum = 0.f, fsS = 0.f;
    float va[6] = {0.f, 0.f, 0.f, 0.f, 0.f, 0.f};
    for (int base = beg; base < end; base += 64) {
        int cnt = end - base;
        if (cnt > 64) cnt = 64;
        int myc = (lane < cnt) ? colb[base + lane] : 0;
        int e = 0;
        for (; e + 3 < cnt; e += 4) {
            uint2 kw[4]; unsigned fC[4]; float4 sc4[4];
#pragma unroll
            for (int u = 0; u < 4; ++u) {
                int s = __builtin_amdgcn_readlane(myc, e + u);  // SGPR, uniform
                const char* rb = nodeP + (size_t)(unsigned)s * ROWB;
                sc4[u] = *(const float4*)rb;                     // uniform addr
                kw[u] = *(const uint2*)(rb + off8);
                fC[u] = *(const unsigned short*)(rb + off2);
            }
            float p[4];
#pragma unroll
            for (int u = 0; u < 4; ++u) {
                float t = qv.x * UB(kw[u].x, 0) + qv.y * UB(kw[u].x, 1);
                t += __shfl_xor(t, 1, 64);
                t += __shfl_xor(t, 2, 64);
                t += __shfl_xor(t, 4, 64);
                p[u] = sc4[u].x * (t - c0q);
            }
            float nm = fmaxf(fmaxf(fmaxf(p[0], p[1]), fmaxf(p[2], p[3])), m);
            float scm = exp2f(m - nm);
            float dsum = 0.f, h0 = 0.f, h1 = 0.f, es = 0.f;
#pragma unroll
            for (int u = 0; u < 4; ++u) {
                float ew = exp2f(p[u] - nm);
                dsum += ew;
                float evs = ew * sc4[u].y;
                h0 += evs * UB(kw[u].x, 2);
                h1 += evs * UB(kw[u].x, 3);
                es += evs;
            }
            d = d * scm + dsum;
            ha0 = ha0 * scm + h0;
            ha1 = ha1 * scm + h1;
            esum = esum * scm + es;
            m = nm;
#pragma unroll
            for (int u = 0; u < 4; ++u) {
                float fs = sc4[u].z;
                va[0] += fs * UB(kw[u].y, 0);
                va[1] += fs * UB(kw[u].y, 1);
                va[2] += fs * UB(kw[u].y, 2);
                va[3] += fs * UB(kw[u].y, 3);
                va[4] += fs * UB(fC[u], 0);
                va[5] += fs * UB(fC[u], 1);
                fsS += fs;
            }
        }
        for (; e < cnt; ++e) {
            int s = __builtin_amdgcn_readlane(myc, e);
            const char* rb = nodeP + (size_t)(unsigned)s * ROWB;
            float4 sc4 = *(const float4*)rb;
            uint2 kw = *(const uint2*)(rb + off8);
            unsigned fC = *(const unsigned short*)(rb + off2);
            float t = qv.x * UB(kw.x, 0) + qv.y * UB(kw.x, 1);
            t += __shfl_xor(t, 1, 64);
            t += __shfl_xor(t, 2, 64);
            t += __shfl_xor(t, 4, 64);
            float p = sc4.x * (t - c0q);
            float nm = fmaxf(m, p);
            float scm = exp2f(m - nm);
            float ew = exp2f(p - nm);
            float evs = ew * sc4.y;
            d = d * scm + ew;
            ha0 = ha0 * scm + evs * UB(kw.x, 2);
            ha1 = ha1 * scm + evs * UB(kw.x, 3);
            esum = esum * scm + evs;
            m = nm;
            float fs = sc4.z;
            va[0] += fs * UB(kw.y, 0);
            va[1] += fs * UB(kw.y, 1);
            va[2] += fs * UB(kw.y, 2);
            va[3] += fs * UB(kw.y, 3);
            va[4] += fs * UB(fC, 0);
            va[5] += fs * UB(fC, 1);
            fsS += fs;
        }
    }
    float inv = (d > 0.f) ? 1.f / d : 0.f;
    float corr = 128.f * esum;
    float ox0 = (ha0 - corr) * inv, ox1 = (ha1 - corr) * inv;
    float fcor = 128.f * fsS;
#pragma unroll
    for (int j = 0; j < 6; ++j) va[j] -= fcor;
    int cc0 = (lane & 7) * 2;
    float accq[6];
#pragma unroll
    for (int jj = 0; jj < 6; jj++) {
        int j = jj >> 1, c = cc0 + (jj & 1);
        accq[jj] = sbp[j * 16 + c];
    }
#pragma unroll
    for (int cp = 0; cp < 16; cp++) {
        int srcLane = (lane & 56) | (cp >> 1);
        float val = __shfl((cp & 1) ? ox1 : ox0, srcLane, 64);
#pragma unroll
        for (int jj = 0; jj < 6; jj++) {
            int j = jj >> 1, c = cc0 + (jj & 1);
            accq[jj] += val * sWp[cp * 48 + j * 16 + c];
        }
    }
    float2 vd2 = make_float2(0.f, 0.f);
#pragma unroll
    for (int s3 = 0; s3 < 3; s3++) {
        const float* vpr = &Cvp[((size_t)node * 3 + s3) * 384 + hh * 48];
        float2 p1 = *(const float2*)&vpr[c0];
        float2 p2 = *(const float2*)&vpr[16 + c0];
        vd2.x += p1.x * p2.x;
        vd2.y += p1.y * p2.y;
    }
    float2 hv = *(const float2*)&hin[(size_t)node * 128 + hc0];
    float2 o0;
    o0.x = hv.x + accq[2] + accq[4] * vd2.x;
    o0.y = hv.y + accq[3] + accq[5] * vd2.y;
    *(float2*)&out0[(size_t)node * 128 + hc0] = o0;
#pragma unroll
    for (int s3 = 0; s3 < 3; s3++) {
        float2 v3 = *(const float2*)&Cvp[((size_t)node * 3 + s3) * 384 + hh * 48 + 32 + c0];
        float2 vv = *(const float2*)&vecin[(size_t)node * 384 + s3 * 128 + hc0];
        float2 o1;
        o1.x = vv.x + v3.x * accq[0] + va[s3 * 2 + 0];
        o1.y = vv.y + v3.y * accq[1] + va[s3 * 2 + 1];
        *(float2*)&out1[(size_t)node * 384 + s3 * 128 + hc0] = o1;
    }
}

extern "C" void kernel_launch(void* const* d_in, const int* in_sizes, int n_in,
                              void* d_out, int out_size, void* d_ws, size_t ws_size,
                              hipStream_t stream) {
    const float* hin = (const float*)d_in[0];
    const float* vec = (const float*)d_in[1];
    const int* ei = (const int*)d_in[2];
    const float* Wq = (const float*)d_in[3];
    const float* bq = (const float*)d_in[4];
    const float* Wk = (const float*)d_in[5];
    const float* bk = (const float*)d_in[6];
    const float* Wv = (const float*)d_in[7];
    const float* bv = (const float*)d_in[8];
    const float* Wp = (const float*)d_in[9];
    const float* bp = (const float*)d_in[10];
    const float* Wvec = (const float*)d_in[11];

    int N = in_sizes[0] / 128;
    int E = in_sizes[2] / 2;
    float* out0 = (float*)d_out;
    float* out1 = out0 + (size_t)N * 128;

    float* wsf = (float*)d_ws;
    size_t off = 0;
    float* Cqkv = wsf + off; off += (size_t)N * 512;
    float* Cvp = wsf + off;  off += (size_t)N * 3 * 384;
    char* nodeP = (char*)(wsf + off); off += ((size_t)N * ROWB + 3) / 4;
    unsigned short* WBT = (unsigned short*)(wsf + off); off += (size_t)512 * 128 / 2;
    unsigned short* WVT = (unsigned short*)(wsf + off); off += (size_t)384 * 128 / 2;
    float* biasAll = wsf + off; off += 512;
    int* ip = (int*)(wsf + off);
    int* deg = ip;            ip += N;
    int* rowptr = ip;         ip += N + 1;
    int* cursor = ip;         ip += N;
    int* colb = ip;           ip += E;

    hipMemsetAsync(deg, 0, (size_t)N * sizeof(int), stream);
    int histBlocks = (E / 4 + 255) / 256;
    int prepBlocks = (512 * 128 + 384 * 128 + 512 + 255) / 256;
    hipLaunchKernelGGL(hist_prep_kernel, dim3(histBlocks + prepBlocks), dim3(256), 0, stream,
                       ei, deg, E, Wq, Wk, Wv, Wvec, bq, bk, bv, WBT, WVT, biasAll, histBlocks);
    hipLaunchKernelGGL(scan_kernel, dim3(1), dim3(1024), 0, stream, deg, rowptr, cursor, N);
    hipLaunchKernelGGL(scatter_kernel, dim3((E / 4 + 255) / 256), dim3(256), 0, stream,
                       ei, cursor, colb, E);
    hipLaunchKernelGGL(gemm_mfma, dim3((N + 127) / 128, 4), dim3(256), 0, stream,
                       hin, WBT, biasAll, Cqkv, N, 512);
    int gbx = (3 * N + 127) / 128;
    int gemmBlocks = gbx * 3;
    int packBlocks = (N + 3) / 4;
    hipLaunchKernelGGL(gemmvec_pack_kernel, dim3(gemmBlocks + packBlocks), dim3(256), 0, stream,
                       vec, WVT, Cvp, 3 * N, gbx, gemmBlocks, Cqkv, nodeP, N);
    hipLaunchKernelGGL(agg_kernel, dim3((N + 3) / 4), dim3(256), 0, stream,
                       rowptr, colb, Cqkv, Cvp, nodeP, hin, vec, Wp, bp, out0, out1, N);
}